// Round 1
// baseline (1098.997 us; speedup 1.0000x reference)
//
#include <hip/hip_runtime.h>

typedef __bf16 bf16x8 __attribute__((ext_vector_type(8)));
typedef float f32x4 __attribute__((ext_vector_type(4)));

struct WPack { const float* p[9]; };

__device__ inline __bf16 f2bf(float f){ return (__bf16)f; }

// Convert 9 fp32 128x128 weight matrices into MFMA B-fragment layout (bf16).
// wf element index: m*16384 + c*2048 + ks*512 + lane*8 + j
//   holds W[k][col], k = ks*32 + (lane>>4)*8 + j, col = c*16 + (lane&15)
__global__ __launch_bounds__(256) void conv_w_kernel(WPack pk, __bf16* __restrict__ wf){
  int tid = blockIdx.x*256 + threadIdx.x;     // 9*16384 threads exactly
  int m = tid >> 14;
  int r = tid & 16383;
  int j = r & 7;
  int lane = (r >> 3) & 63;
  int ks = (r >> 9) & 3;
  int c = r >> 11;
  int k = ks*32 + ((lane>>4)<<3) + j;
  int col = (c<<4) + (lane & 15);
  wf[tid] = f2bf(pk.p[m][k*128 + col]);
}

__global__ __launch_bounds__(256) void hist_kernel(const int* __restrict__ ei, int E, int* __restrict__ deg){
  int i = blockIdx.x*256 + threadIdx.x;
  if (i < E) atomicAdd(&deg[ei[E + i]], 1);   // dst row
}

__global__ __launch_bounds__(1024) void scan_kernel(const int* __restrict__ deg, int* __restrict__ rs, int N){
  __shared__ int part[1024];
  int t = threadIdx.x;
  int chunk = (N + 1023) >> 10;
  int lo = t*chunk, hi = lo + chunk; if (hi > N) hi = N;
  int s = 0;
  for (int i = lo; i < hi; i++) s += deg[i];
  part[t] = s; __syncthreads();
  for (int off = 1; off < 1024; off <<= 1){
    int v = (t >= off) ? part[t-off] : 0;
    __syncthreads();
    part[t] += v;
    __syncthreads();
  }
  int excl = (t == 0) ? 0 : part[t-1];
  for (int i = lo; i < hi; i++){ rs[i] = excl; excl += deg[i]; }
  if (t == 1023) rs[N] = part[1023];
}

__global__ __launch_bounds__(256) void fill_kernel(const int* __restrict__ ei, int E,
    const int* __restrict__ rs, int* __restrict__ cur, int* __restrict__ csr){
  int i = blockIdx.x*256 + threadIdx.x;
  if (i < E){
    int s = ei[i];
    int d = ei[E + i];
    int p = atomicAdd(&cur[d], 1);
    csr[rs[d] + p] = s;
  }
}

// h[i] = x[i] + sum_{j in N(i)} x[j]; one wave per node, float2 per lane.
__global__ __launch_bounds__(256) void agg_kernel(const float* __restrict__ x,
    const int* __restrict__ rs, const int* __restrict__ csr,
    float* __restrict__ h, int N)
{
  int node = blockIdx.x*4 + (threadIdx.x >> 6);
  if (node >= N) return;
  int lane = threadIdx.x & 63;
  int s = rs[node], e = rs[node+1];
  float2 acc = ((const float2*)(x + (long)node*128))[lane];
  for (int base = s; base < e; base += 64){
    int idx = base + lane;
    int nb = (idx < e) ? csr[idx] : 0;
    int cnt = e - base; if (cnt > 64) cnt = 64;
    for (int t = 0; t < cnt; t++){
      int srcn = __shfl(nb, t);
      float2 v = ((const float2*)(x + (long)srcn*128))[lane];
      acc.x += v.x; acc.y += v.y;
    }
  }
  ((float2*)(h + (long)node*128))[lane] = acc;
}

// C[M,128] = act(A[M,128] @ W + bias [+ res]) [+= out]
// Block: 256 thr = 4 waves; each wave owns a 32-col stripe, loops 8 row-tiles (128 rows/block).
// W held in registers as 8 B-fragments (loaded once). In-place A==out safe via per-tile barrier.
template<int ACT, bool RES, bool ACCUM>
__global__ __launch_bounds__(256) void gemm128(const float* __restrict__ A,
    const __bf16* __restrict__ wf, const float* __restrict__ bias,
    const float* __restrict__ res, float* __restrict__ out, int M)
{
  int lane = threadIdx.x & 63;
  int wid = threadIdx.x >> 6;
  long row0 = (long)blockIdx.x * 128;
  const bf16x8* wfv = (const bf16x8*)wf;
  bf16x8 bv[2][4];
  #pragma unroll
  for (int c2 = 0; c2 < 2; c2++)
    #pragma unroll
    for (int ks = 0; ks < 4; ks++)
      bv[c2][ks] = wfv[((wid*2 + c2)*4 + ks)*64 + lane];
  int col0 = wid*32 + (lane & 15);
  float b0 = 0.f, b1 = 0.f;
  if (bias){ b0 = bias[col0]; b1 = bias[col0 + 16]; }
  int koff = (lane >> 4) << 3;
  #pragma unroll 1
  for (int rt = 0; rt < 8; rt++){
    long row = row0 + rt*16 + (lane & 15);
    long rowc = (row < M) ? row : (long)(M-1);
    const float* ap = A + rowc*128 + koff;
    f32x4 u[8];
    #pragma unroll
    for (int ks = 0; ks < 4; ks++){
      u[2*ks]   = *(const f32x4*)(ap + ks*32);
      u[2*ks+1] = *(const f32x4*)(ap + ks*32 + 4);
    }
    __syncthreads();   // all waves' loads of this tile complete before any in-place write
    f32x4 acc0 = {0.f,0.f,0.f,0.f}, acc1 = {0.f,0.f,0.f,0.f};
    #pragma unroll
    for (int ks = 0; ks < 4; ks++){
      f32x4 a0 = u[2*ks], a1 = u[2*ks+1];
      bf16x8 av;
      av[0]=f2bf(a0[0]); av[1]=f2bf(a0[1]); av[2]=f2bf(a0[2]); av[3]=f2bf(a0[3]);
      av[4]=f2bf(a1[0]); av[5]=f2bf(a1[1]); av[6]=f2bf(a1[2]); av[7]=f2bf(a1[3]);
      acc0 = __builtin_amdgcn_mfma_f32_16x16x32_bf16(av, bv[0][ks], acc0, 0, 0, 0);
      acc1 = __builtin_amdgcn_mfma_f32_16x16x32_bf16(av, bv[1][ks], acc1, 0, 0, 0);
    }
    long orow0 = row0 + rt*16 + ((lane >> 4) << 2);
    #pragma unroll
    for (int c2 = 0; c2 < 2; c2++){
      f32x4 acc = c2 ? acc1 : acc0;
      int col = col0 + c2*16;
      float bb = c2 ? b1 : b0;
      #pragma unroll
      for (int i = 0; i < 4; i++){
        long orow = orow0 + i;
        if (orow < M){
          long idx = orow*128 + col;
          float v = acc[i] + bb;
          if (RES) v += res[idx];
          if (ACT == 1) v = fmaxf(v, 0.f);
          if (ACT == 2) v = (v > 0.f) ? v : (__expf(v) - 1.f);
          if (ACCUM) v += out[idx];
          out[idx] = v;
        }
      }
    }
  }
}

extern "C" void kernel_launch(void* const* d_in, const int* in_sizes, int n_in,
                              void* d_out, int out_size, void* d_ws, size_t ws_size,
                              hipStream_t stream)
{
  const float* x   = (const float*)d_in[0];
  const int*   ei  = (const int*)d_in[1];
  const float* w1[3] = {(const float*)d_in[2], (const float*)d_in[6], (const float*)d_in[10]};
  const float* b1[3] = {(const float*)d_in[3], (const float*)d_in[7], (const float*)d_in[11]};
  const float* w2[3] = {(const float*)d_in[4], (const float*)d_in[8], (const float*)d_in[12]};
  const float* b2[3] = {(const float*)d_in[5], (const float*)d_in[9], (const float*)d_in[13]};
  const float* jkw = (const float*)d_in[14];
  const float* jkb = (const float*)d_in[15];
  int N = in_sizes[0] / 128;
  int E = in_sizes[1] / 2;
  float* outp = (float*)d_out;

  char* wptr = (char*)d_ws;
  auto alloc = [&](size_t bytes)->void*{
    void* p = (void*)wptr; wptr += (bytes + 255) & ~(size_t)255; return p;
  };
  int* deg = (int*)alloc((size_t)N*4);
  int* rs  = (int*)alloc((size_t)(N+1)*4);
  int* cur = (int*)alloc((size_t)N*4);
  int* csr = (int*)alloc((size_t)E*4);
  float* xa = (float*)alloc((size_t)N*128*4);
  float* h  = (float*)alloc((size_t)N*128*4);
  __bf16* wf = (__bf16*)alloc((size_t)9*16384*2);

  hipMemsetAsync(deg, 0, (size_t)N*4, stream);
  hipMemsetAsync(cur, 0, (size_t)N*4, stream);

  WPack pk;
  pk.p[0] = w1[0]; pk.p[1] = w2[0];
  pk.p[2] = w1[1]; pk.p[3] = w2[1];
  pk.p[4] = w1[2]; pk.p[5] = w2[2];
  pk.p[6] = jkw; pk.p[7] = jkw + 16384; pk.p[8] = jkw + 32768;
  conv_w_kernel<<<576, 256, 0, stream>>>(pk, wf);

  hist_kernel<<<(E + 255)/256, 256, 0, stream>>>(ei, E, deg);
  scan_kernel<<<1, 1024, 0, stream>>>(deg, rs, N);
  fill_kernel<<<(E + 255)/256, 256, 0, stream>>>(ei, E, rs, cur, csr);

  int gemm_blocks = (N + 127)/128;
  for (int l = 0; l < 3; l++){
    const float* xin = (l == 0) ? x : xa;
    agg_kernel<<<(N + 3)/4, 256, 0, stream>>>(xin, rs, csr, h, N);
    // h = relu(h @ w1 + b1)  (in place, barrier-protected)
    gemm128<1,false,false><<<gemm_blocks, 256, 0, stream>>>(h, wf + (size_t)(2*l)*16384, b1[l], nullptr, h, N);
    // xa = [elu](h @ w2 + b2 + xin)
    if (l < 2)
      gemm128<2,true,false><<<gemm_blocks, 256, 0, stream>>>(h, wf + (size_t)(2*l+1)*16384, b2[l], xin, xa, N);
    else
      gemm128<0,true,false><<<gemm_blocks, 256, 0, stream>>>(h, wf + (size_t)(2*l+1)*16384, b2[l], xin, xa, N);
    // out (+)= xa @ jk_w[l] (+ jk_b on l==0)
    if (l == 0)
      gemm128<0,false,false><<<gemm_blocks, 256, 0, stream>>>(xa, wf + (size_t)(6+l)*16384, jkb, nullptr, outp, N);
    else
      gemm128<0,false,true><<<gemm_blocks, 256, 0, stream>>>(xa, wf + (size_t)(6+l)*16384, nullptr, nullptr, outp, N);
  }
}

// Round 2
// 946.998 us; speedup vs baseline: 1.1605x; 1.1605x over previous
//
#include <hip/hip_runtime.h>

typedef __bf16 bf16x8 __attribute__((ext_vector_type(8)));
typedef float f32x4 __attribute__((ext_vector_type(4)));

struct WPack { const float* p[9]; };

__device__ inline __bf16 f2bf(float f){ return (__bf16)f; }

// Convert 9 fp32 128x128 weight matrices into MFMA B-fragment layout (bf16).
// wf element index: m*16384 + c*2048 + ks*512 + lane*8 + j
//   holds W[k][col], k = ks*32 + (lane>>4)*8 + j, col = c*16 + (lane&15)
__global__ __launch_bounds__(256) void conv_w_kernel(WPack pk, __bf16* __restrict__ wf){
  int tid = blockIdx.x*256 + threadIdx.x;     // 9*16384 threads exactly
  int m = tid >> 14;
  int r = tid & 16383;
  int j = r & 7;
  int lane = (r >> 3) & 63;
  int ks = (r >> 9) & 3;
  int c = r >> 11;
  int k = ks*32 + ((lane>>4)<<3) + j;
  int col = (c<<4) + (lane & 15);
  wf[tid] = f2bf(pk.p[m][k*128 + col]);
}

__global__ __launch_bounds__(256) void hist_kernel(const int* __restrict__ ei, int E, int* __restrict__ deg){
  int i = blockIdx.x*256 + threadIdx.x;
  if (i < E) atomicAdd(&deg[ei[E + i]], 1);   // dst row
}

// ---- 3-phase parallel exclusive scan of deg[N] -> rs[N] (+ rs[N]=total) ----
// 2048 elements per 256-thread block.
__global__ __launch_bounds__(256) void scan1_kernel(const int* __restrict__ deg, int* __restrict__ bsum, int N){
  __shared__ int sh[256];
  int b = blockIdx.x, t = threadIdx.x;
  int base = b*2048 + t*8;
  int s = 0;
  #pragma unroll
  for (int j = 0; j < 8; j++){ int i = base + j; if (i < N) s += deg[i]; }
  sh[t] = s; __syncthreads();
  for (int off = 128; off > 0; off >>= 1){
    if (t < off) sh[t] += sh[t + off];
    __syncthreads();
  }
  if (t == 0) bsum[b] = sh[0];
}

// single block; NB <= 256 partials. Writes exclusive block offsets + total into rs[N].
__global__ __launch_bounds__(256) void scan2_kernel(const int* __restrict__ bsum, int* __restrict__ boff,
                                                    int NB, int* __restrict__ rs_total){
  __shared__ int sh[256];
  int t = threadIdx.x;
  int v = (t < NB) ? bsum[t] : 0;
  sh[t] = v; __syncthreads();
  for (int off = 1; off < 256; off <<= 1){
    int u = (t >= off) ? sh[t - off] : 0;
    __syncthreads();
    sh[t] += u;
    __syncthreads();
  }
  if (t < NB) boff[t] = sh[t] - v;          // exclusive
  if (t == 255) *rs_total = sh[255];        // rs[N] = E
}

__global__ __launch_bounds__(256) void scan3_kernel(const int* __restrict__ deg, const int* __restrict__ boff,
                                                    int* __restrict__ rs, int N){
  __shared__ int sh[256];
  int b = blockIdx.x, t = threadIdx.x;
  int base = b*2048 + t*8;
  int loc[8]; int s = 0;
  #pragma unroll
  for (int j = 0; j < 8; j++){ int i = base + j; int d = (i < N) ? deg[i] : 0; loc[j] = d; s += d; }
  sh[t] = s; __syncthreads();
  for (int off = 1; off < 256; off <<= 1){
    int u = (t >= off) ? sh[t - off] : 0;
    __syncthreads();
    sh[t] += u;
    __syncthreads();
  }
  int excl = boff[b] + sh[t] - s;
  #pragma unroll
  for (int j = 0; j < 8; j++){ int i = base + j; if (i < N) rs[i] = excl; excl += loc[j]; }
}

__global__ __launch_bounds__(256) void fill_kernel(const int* __restrict__ ei, int E,
    const int* __restrict__ rs, int* __restrict__ cur, int* __restrict__ csr){
  int i = blockIdx.x*256 + threadIdx.x;
  if (i < E){
    int s = ei[i];
    int d = ei[E + i];
    int p = atomicAdd(&cur[d], 1);
    csr[rs[d] + p] = s;
  }
}

// h[i] = x[i] + sum_{j in N(i)} x[j]; one wave per node, float2 per lane.
__global__ __launch_bounds__(256) void agg_kernel(const float* __restrict__ x,
    const int* __restrict__ rs, const int* __restrict__ csr,
    float* __restrict__ h, int N)
{
  int node = blockIdx.x*4 + (threadIdx.x >> 6);
  if (node >= N) return;
  int lane = threadIdx.x & 63;
  int s = rs[node], e = rs[node+1];
  float2 acc = ((const float2*)(x + (long)node*128))[lane];
  for (int base = s; base < e; base += 64){
    int idx = base + lane;
    int nb = (idx < e) ? csr[idx] : 0;
    int cnt = e - base; if (cnt > 64) cnt = 64;
    for (int t = 0; t < cnt; t++){
      int srcn = __shfl(nb, t);
      float2 v = ((const float2*)(x + (long)srcn*128))[lane];
      acc.x += v.x; acc.y += v.y;
    }
  }
  ((float2*)(h + (long)node*128))[lane] = acc;
}

// C[M,128] = act(A[M,128] @ W + bias [+ res]) [+= out]
// Block: 256 thr = 4 waves; each wave owns a 32-col stripe, loops 8 row-tiles (128 rows/block).
// W held in registers as 8 B-fragments (loaded once). In-place A==out safe via per-tile barrier.
template<int ACT, bool RES, bool ACCUM>
__global__ __launch_bounds__(256) void gemm128(const float* __restrict__ A,
    const __bf16* __restrict__ wf, const float* __restrict__ bias,
    const float* __restrict__ res, float* __restrict__ out, int M)
{
  int lane = threadIdx.x & 63;
  int wid = threadIdx.x >> 6;
  long row0 = (long)blockIdx.x * 128;
  const bf16x8* wfv = (const bf16x8*)wf;
  bf16x8 bv[2][4];
  #pragma unroll
  for (int c2 = 0; c2 < 2; c2++)
    #pragma unroll
    for (int ks = 0; ks < 4; ks++)
      bv[c2][ks] = wfv[((wid*2 + c2)*4 + ks)*64 + lane];
  int col0 = wid*32 + (lane & 15);
  float b0 = 0.f, b1 = 0.f;
  if (bias){ b0 = bias[col0]; b1 = bias[col0 + 16]; }
  int koff = (lane >> 4) << 3;
  #pragma unroll 1
  for (int rt = 0; rt < 8; rt++){
    long row = row0 + rt*16 + (lane & 15);
    long rowc = (row < M) ? row : (long)(M-1);
    const float* ap = A + rowc*128 + koff;
    f32x4 u[8];
    #pragma unroll
    for (int ks = 0; ks < 4; ks++){
      u[2*ks]   = *(const f32x4*)(ap + ks*32);
      u[2*ks+1] = *(const f32x4*)(ap + ks*32 + 4);
    }
    __syncthreads();   // all waves' loads of this tile complete before any in-place write
    f32x4 acc0 = {0.f,0.f,0.f,0.f}, acc1 = {0.f,0.f,0.f,0.f};
    #pragma unroll
    for (int ks = 0; ks < 4; ks++){
      f32x4 a0 = u[2*ks], a1 = u[2*ks+1];
      bf16x8 av;
      av[0]=f2bf(a0[0]); av[1]=f2bf(a0[1]); av[2]=f2bf(a0[2]); av[3]=f2bf(a0[3]);
      av[4]=f2bf(a1[0]); av[5]=f2bf(a1[1]); av[6]=f2bf(a1[2]); av[7]=f2bf(a1[3]);
      acc0 = __builtin_amdgcn_mfma_f32_16x16x32_bf16(av, bv[0][ks], acc0, 0, 0, 0);
      acc1 = __builtin_amdgcn_mfma_f32_16x16x32_bf16(av, bv[1][ks], acc1, 0, 0, 0);
    }
    long orow0 = row0 + rt*16 + ((lane >> 4) << 2);
    #pragma unroll
    for (int c2 = 0; c2 < 2; c2++){
      f32x4 acc = c2 ? acc1 : acc0;
      int col = col0 + c2*16;
      float bb = c2 ? b1 : b0;
      #pragma unroll
      for (int i = 0; i < 4; i++){
        long orow = orow0 + i;
        if (orow < M){
          long idx = orow*128 + col;
          float v = acc[i] + bb;
          if (RES) v += res[idx];
          if (ACT == 1) v = fmaxf(v, 0.f);
          if (ACT == 2) v = (v > 0.f) ? v : (__expf(v) - 1.f);
          if (ACCUM) v += out[idx];
          out[idx] = v;
        }
      }
    }
  }
}

extern "C" void kernel_launch(void* const* d_in, const int* in_sizes, int n_in,
                              void* d_out, int out_size, void* d_ws, size_t ws_size,
                              hipStream_t stream)
{
  const float* x   = (const float*)d_in[0];
  const int*   ei  = (const int*)d_in[1];
  const float* w1[3] = {(const float*)d_in[2], (const float*)d_in[6], (const float*)d_in[10]};
  const float* b1[3] = {(const float*)d_in[3], (const float*)d_in[7], (const float*)d_in[11]};
  const float* w2[3] = {(const float*)d_in[4], (const float*)d_in[8], (const float*)d_in[12]};
  const float* b2[3] = {(const float*)d_in[5], (const float*)d_in[9], (const float*)d_in[13]};
  const float* jkw = (const float*)d_in[14];
  const float* jkb = (const float*)d_in[15];
  int N = in_sizes[0] / 128;
  int E = in_sizes[1] / 2;
  float* outp = (float*)d_out;

  char* wptr = (char*)d_ws;
  auto alloc = [&](size_t bytes)->void*{
    void* p = (void*)wptr; wptr += (bytes + 255) & ~(size_t)255; return p;
  };
  int* deg = (int*)alloc((size_t)N*4);
  int* rs  = (int*)alloc((size_t)(N+1)*4);
  int* cur = (int*)alloc((size_t)N*4);
  int* csr = (int*)alloc((size_t)E*4);
  float* xa = (float*)alloc((size_t)N*128*4);
  float* h  = (float*)alloc((size_t)N*128*4);
  __bf16* wf = (__bf16*)alloc((size_t)9*16384*2);
  int nsb = (N + 2047) / 2048;                 // scan blocks (49 for N=100K)
  int* bsum = (int*)alloc((size_t)nsb*4);
  int* boff = (int*)alloc((size_t)nsb*4);

  hipMemsetAsync(deg, 0, (size_t)N*4, stream);
  hipMemsetAsync(cur, 0, (size_t)N*4, stream);

  WPack pk;
  pk.p[0] = w1[0]; pk.p[1] = w2[0];
  pk.p[2] = w1[1]; pk.p[3] = w2[1];
  pk.p[4] = w1[2]; pk.p[5] = w2[2];
  pk.p[6] = jkw; pk.p[7] = jkw + 16384; pk.p[8] = jkw + 32768;
  conv_w_kernel<<<576, 256, 0, stream>>>(pk, wf);

  hist_kernel<<<(E + 255)/256, 256, 0, stream>>>(ei, E, deg);
  scan1_kernel<<<nsb, 256, 0, stream>>>(deg, bsum, N);
  scan2_kernel<<<1, 256, 0, stream>>>(bsum, boff, nsb, rs + N);
  scan3_kernel<<<nsb, 256, 0, stream>>>(deg, boff, rs, N);
  fill_kernel<<<(E + 255)/256, 256, 0, stream>>>(ei, E, rs, cur, csr);

  int gemm_blocks = (N + 127)/128;
  for (int l = 0; l < 3; l++){
    const float* xin = (l == 0) ? x : xa;
    agg_kernel<<<(N + 3)/4, 256, 0, stream>>>(xin, rs, csr, h, N);
    // h = relu(h @ w1 + b1)  (in place, barrier-protected)
    gemm128<1,false,false><<<gemm_blocks, 256, 0, stream>>>(h, wf + (size_t)(2*l)*16384, b1[l], nullptr, h, N);
    // xa = [elu](h @ w2 + b2 + xin)
    if (l < 2)
      gemm128<2,true,false><<<gemm_blocks, 256, 0, stream>>>(h, wf + (size_t)(2*l+1)*16384, b2[l], xin, xa, N);
    else
      gemm128<0,true,false><<<gemm_blocks, 256, 0, stream>>>(h, wf + (size_t)(2*l+1)*16384, b2[l], xin, xa, N);
    // out (+)= xa @ jk_w[l] (+ jk_b on l==0)
    if (l == 0)
      gemm128<0,false,false><<<gemm_blocks, 256, 0, stream>>>(xa, wf + (size_t)(6+l)*16384, jkb, nullptr, outp, N);
    else
      gemm128<0,false,true><<<gemm_blocks, 256, 0, stream>>>(xa, wf + (size_t)(6+l)*16384, nullptr, nullptr, outp, N);
  }
}

// Round 3
// 656.536 us; speedup vs baseline: 1.6739x; 1.4424x over previous
//
#include <hip/hip_runtime.h>

typedef __bf16 bf16x8 __attribute__((ext_vector_type(8)));
typedef __bf16 bf16x2 __attribute__((ext_vector_type(2)));
typedef float f32x4 __attribute__((ext_vector_type(4)));

struct WPack { const float* p[9]; };

__device__ inline __bf16 f2bf(float f){ return (__bf16)f; }

// Convert 9 fp32 128x128 weight matrices into MFMA B-fragment layout (bf16).
// wf element index: m*16384 + c*2048 + ks*512 + lane*8 + j
//   holds W[k][col], k = ks*32 + (lane>>4)*8 + j, col = c*16 + (lane&15)
__global__ __launch_bounds__(256) void conv_w_kernel(WPack pk, __bf16* __restrict__ wf){
  int tid = blockIdx.x*256 + threadIdx.x;     // 9*16384 threads exactly
  int m = tid >> 14;
  int r = tid & 16383;
  int j = r & 7;
  int lane = (r >> 3) & 63;
  int ks = (r >> 9) & 3;
  int c = r >> 11;
  int k = ks*32 + ((lane>>4)<<3) + j;
  int col = (c<<4) + (lane & 15);
  wf[tid] = f2bf(pk.p[m][k*128 + col]);
}

// fp32 -> bf16 bulk convert, 8 elems/thread
__global__ __launch_bounds__(256) void f2b_kernel(const float* __restrict__ x, __bf16* __restrict__ xb, int n8){
  int i = blockIdx.x*256 + threadIdx.x;
  if (i >= n8) return;
  f32x4 a = ((const f32x4*)x)[2*i];
  f32x4 b = ((const f32x4*)x)[2*i+1];
  bf16x8 r;
  r[0]=f2bf(a[0]); r[1]=f2bf(a[1]); r[2]=f2bf(a[2]); r[3]=f2bf(a[3]);
  r[4]=f2bf(b[0]); r[5]=f2bf(b[1]); r[6]=f2bf(b[2]); r[7]=f2bf(b[3]);
  ((bf16x8*)xb)[i] = r;
}

__global__ __launch_bounds__(256) void hist_kernel(const int* __restrict__ ei, int E, int* __restrict__ deg){
  int i = blockIdx.x*256 + threadIdx.x;
  if (i < E) atomicAdd(&deg[ei[E + i]], 1);   // dst row
}

// ---- 3-phase parallel exclusive scan of deg[N] -> rs[N] (+ rs[N]=total) ----
__global__ __launch_bounds__(256) void scan1_kernel(const int* __restrict__ deg, int* __restrict__ bsum, int N){
  __shared__ int sh[256];
  int b = blockIdx.x, t = threadIdx.x;
  int base = b*2048 + t*8;
  int s = 0;
  #pragma unroll
  for (int j = 0; j < 8; j++){ int i = base + j; if (i < N) s += deg[i]; }
  sh[t] = s; __syncthreads();
  for (int off = 128; off > 0; off >>= 1){
    if (t < off) sh[t] += sh[t + off];
    __syncthreads();
  }
  if (t == 0) bsum[b] = sh[0];
}

__global__ __launch_bounds__(256) void scan2_kernel(const int* __restrict__ bsum, int* __restrict__ boff,
                                                    int NB, int* __restrict__ rs_total){
  __shared__ int sh[256];
  int t = threadIdx.x;
  int v = (t < NB) ? bsum[t] : 0;
  sh[t] = v; __syncthreads();
  for (int off = 1; off < 256; off <<= 1){
    int u = (t >= off) ? sh[t - off] : 0;
    __syncthreads();
    sh[t] += u;
    __syncthreads();
  }
  if (t < NB) boff[t] = sh[t] - v;          // exclusive
  if (t == 255) *rs_total = sh[255];        // rs[N] = E
}

__global__ __launch_bounds__(256) void scan3_kernel(const int* __restrict__ deg, const int* __restrict__ boff,
                                                    int* __restrict__ rs, int N){
  __shared__ int sh[256];
  int b = blockIdx.x, t = threadIdx.x;
  int base = b*2048 + t*8;
  int loc[8]; int s = 0;
  #pragma unroll
  for (int j = 0; j < 8; j++){ int i = base + j; int d = (i < N) ? deg[i] : 0; loc[j] = d; s += d; }
  sh[t] = s; __syncthreads();
  for (int off = 1; off < 256; off <<= 1){
    int u = (t >= off) ? sh[t - off] : 0;
    __syncthreads();
    sh[t] += u;
    __syncthreads();
  }
  int excl = boff[b] + sh[t] - s;
  #pragma unroll
  for (int j = 0; j < 8; j++){ int i = base + j; if (i < N) rs[i] = excl; excl += loc[j]; }
}

__global__ __launch_bounds__(256) void fill_kernel(const int* __restrict__ ei, int E,
    const int* __restrict__ rs, int* __restrict__ cur, int* __restrict__ csr){
  int i = blockIdx.x*256 + threadIdx.x;
  if (i < E){
    int s = ei[i];
    int d = ei[E + i];
    int p = atomicAdd(&cur[d], 1);
    csr[rs[d] + p] = s;
  }
}

// h[i] = x[i] + sum_{j in N(i)} x[j]; one wave per node, bf16x2 (4B) per lane, fp32 accum.
__global__ __launch_bounds__(256) void agg_kernel(const __bf16* __restrict__ xb,
    const int* __restrict__ rs, const int* __restrict__ csr,
    __bf16* __restrict__ hb, int N)
{
  int node = blockIdx.x*4 + (threadIdx.x >> 6);
  if (node >= N) return;
  int lane = threadIdx.x & 63;
  int s = rs[node], e = rs[node+1];
  bf16x2 self = ((const bf16x2*)(xb + (long)node*128))[lane];
  float a0 = (float)self[0], a1 = (float)self[1];
  for (int base = s; base < e; base += 64){
    int idx = base + lane;
    int nb = (idx < e) ? csr[idx] : 0;
    int cnt = e - base; if (cnt > 64) cnt = 64;
    int t = 0;
    for (; t + 1 < cnt; t += 2){
      int s0 = __shfl(nb, t);
      int s1 = __shfl(nb, t+1);
      bf16x2 v0 = ((const bf16x2*)(xb + (long)s0*128))[lane];
      bf16x2 v1 = ((const bf16x2*)(xb + (long)s1*128))[lane];
      a0 += (float)v0[0] + (float)v1[0];
      a1 += (float)v0[1] + (float)v1[1];
    }
    if (t < cnt){
      int s0 = __shfl(nb, t);
      bf16x2 v0 = ((const bf16x2*)(xb + (long)s0*128))[lane];
      a0 += (float)v0[0];
      a1 += (float)v0[1];
    }
  }
  bf16x2 r; r[0] = f2bf(a0); r[1] = f2bf(a1);
  ((bf16x2*)(hb + (long)node*128))[lane] = r;
}

// C[M,128] = act(A[M,128] @ W + bias [+ res]) ; out bf16, or fp32 (+= out) for JK.
// Block: 256 thr = 4 waves; each wave owns a 32-col stripe, loops 8 row-tiles (128 rows/block).
// A is bf16 — fragments load directly as bf16x8. In-place A==out safe via per-tile barrier.
template<int ACT, bool RES, bool ACCUM, bool OUTBF>
__global__ __launch_bounds__(256) void gemm128(const __bf16* __restrict__ A,
    const __bf16* __restrict__ wf, const float* __restrict__ bias,
    const __bf16* __restrict__ res, float* __restrict__ outf, __bf16* __restrict__ outb, int M)
{
  int lane = threadIdx.x & 63;
  int wid = threadIdx.x >> 6;
  long row0 = (long)blockIdx.x * 128;
  const bf16x8* wfv = (const bf16x8*)wf;
  bf16x8 bv[2][4];
  #pragma unroll
  for (int c2 = 0; c2 < 2; c2++)
    #pragma unroll
    for (int ks = 0; ks < 4; ks++)
      bv[c2][ks] = wfv[((wid*2 + c2)*4 + ks)*64 + lane];
  int col0 = wid*32 + (lane & 15);
  float b0 = 0.f, b1 = 0.f;
  if (bias){ b0 = bias[col0]; b1 = bias[col0 + 16]; }
  int koff = (lane >> 4) << 3;
  #pragma unroll 1
  for (int rt = 0; rt < 8; rt++){
    long row = row0 + rt*16 + (lane & 15);
    long rowc = (row < M) ? row : (long)(M-1);
    const __bf16* ap = A + rowc*128 + koff;
    bf16x8 av[4];
    #pragma unroll
    for (int ks = 0; ks < 4; ks++)
      av[ks] = *(const bf16x8*)(ap + ks*32);
    __syncthreads();   // all waves' loads of this tile complete before any in-place write
    f32x4 acc0 = {0.f,0.f,0.f,0.f}, acc1 = {0.f,0.f,0.f,0.f};
    #pragma unroll
    for (int ks = 0; ks < 4; ks++){
      acc0 = __builtin_amdgcn_mfma_f32_16x16x32_bf16(av[ks], bv[0][ks], acc0, 0, 0, 0);
      acc1 = __builtin_amdgcn_mfma_f32_16x16x32_bf16(av[ks], bv[1][ks], acc1, 0, 0, 0);
    }
    long orow0 = row0 + rt*16 + ((lane >> 4) << 2);
    #pragma unroll
    for (int c2 = 0; c2 < 2; c2++){
      f32x4 acc = c2 ? acc1 : acc0;
      int col = col0 + c2*16;
      float bb = c2 ? b1 : b0;
      #pragma unroll
      for (int i = 0; i < 4; i++){
        long orow = orow0 + i;
        if (orow < M){
          long idx = orow*128 + col;
          float v = acc[i] + bb;
          if (RES) v += (float)res[idx];
          if (ACT == 1) v = fmaxf(v, 0.f);
          if (ACT == 2) v = (v > 0.f) ? v : (__expf(v) - 1.f);
          if (ACCUM) v += outf[idx];
          if (OUTBF) outb[idx] = f2bf(v);
          else       outf[idx] = v;
        }
      }
    }
  }
}

extern "C" void kernel_launch(void* const* d_in, const int* in_sizes, int n_in,
                              void* d_out, int out_size, void* d_ws, size_t ws_size,
                              hipStream_t stream)
{
  const float* x   = (const float*)d_in[0];
  const int*   ei  = (const int*)d_in[1];
  const float* w1[3] = {(const float*)d_in[2], (const float*)d_in[6], (const float*)d_in[10]};
  const float* b1[3] = {(const float*)d_in[3], (const float*)d_in[7], (const float*)d_in[11]};
  const float* w2[3] = {(const float*)d_in[4], (const float*)d_in[8], (const float*)d_in[12]};
  const float* b2[3] = {(const float*)d_in[5], (const float*)d_in[9], (const float*)d_in[13]};
  const float* jkw = (const float*)d_in[14];
  const float* jkb = (const float*)d_in[15];
  int N = in_sizes[0] / 128;
  int E = in_sizes[1] / 2;
  float* outp = (float*)d_out;

  char* wptr = (char*)d_ws;
  auto alloc = [&](size_t bytes)->void*{
    void* p = (void*)wptr; wptr += (bytes + 255) & ~(size_t)255; return p;
  };
  int* deg = (int*)alloc((size_t)N*4);
  int* rs  = (int*)alloc((size_t)(N+1)*4);
  int* cur = (int*)alloc((size_t)N*4);
  int* csr = (int*)alloc((size_t)E*4);
  __bf16* xb  = (__bf16*)alloc((size_t)N*128*2);  // bf16(x)
  __bf16* xab = (__bf16*)alloc((size_t)N*128*2);  // layer outputs (bf16)
  __bf16* hb  = (__bf16*)alloc((size_t)N*128*2);  // agg out / mlp hidden (bf16)
  __bf16* wf  = (__bf16*)alloc((size_t)9*16384*2);
  int nsb = (N + 2047) / 2048;                 // scan blocks (49 for N=100K)
  int* bsum = (int*)alloc((size_t)nsb*4);
  int* boff = (int*)alloc((size_t)nsb*4);

  hipMemsetAsync(deg, 0, (size_t)N*4, stream);
  hipMemsetAsync(cur, 0, (size_t)N*4, stream);

  WPack pk;
  pk.p[0] = w1[0]; pk.p[1] = w2[0];
  pk.p[2] = w1[1]; pk.p[3] = w2[1];
  pk.p[4] = w1[2]; pk.p[5] = w2[2];
  pk.p[6] = jkw; pk.p[7] = jkw + 16384; pk.p[8] = jkw + 32768;
  conv_w_kernel<<<576, 256, 0, stream>>>(pk, wf);

  f2b_kernel<<<(N*128/8 + 255)/256, 256, 0, stream>>>(x, xb, N*128/8);

  hist_kernel<<<(E + 255)/256, 256, 0, stream>>>(ei, E, deg);
  scan1_kernel<<<nsb, 256, 0, stream>>>(deg, bsum, N);
  scan2_kernel<<<1, 256, 0, stream>>>(bsum, boff, nsb, rs + N);
  scan3_kernel<<<nsb, 256, 0, stream>>>(deg, boff, rs, N);
  fill_kernel<<<(E + 255)/256, 256, 0, stream>>>(ei, E, rs, cur, csr);

  int gemm_blocks = (N + 127)/128;
  for (int l = 0; l < 3; l++){
    const __bf16* xin = (l == 0) ? xb : xab;
    agg_kernel<<<(N + 3)/4, 256, 0, stream>>>(xin, rs, csr, hb, N);
    // hb = relu(hb @ w1 + b1)  (in place, barrier-protected)
    gemm128<1,false,false,true><<<gemm_blocks, 256, 0, stream>>>(hb, wf + (size_t)(2*l)*16384, b1[l], nullptr, nullptr, hb, N);
    // xab = [elu](hb @ w2 + b2 + xin)   (xin==xab for l>0: per-element RMW, safe)
    if (l < 2)
      gemm128<2,true,false,true><<<gemm_blocks, 256, 0, stream>>>(hb, wf + (size_t)(2*l+1)*16384, b2[l], xin, nullptr, xab, N);
    else
      gemm128<0,true,false,true><<<gemm_blocks, 256, 0, stream>>>(hb, wf + (size_t)(2*l+1)*16384, b2[l], xin, nullptr, xab, N);
    // out (+)= xab @ jk_w[l] (+ jk_b on l==0)
    if (l == 0)
      gemm128<0,false,false,false><<<gemm_blocks, 256, 0, stream>>>(xab, wf + (size_t)(6+l)*16384, jkb, nullptr, outp, nullptr, N);
    else
      gemm128<0,false,true,false><<<gemm_blocks, 256, 0, stream>>>(xab, wf + (size_t)(6+l)*16384, nullptr, nullptr, outp, nullptr, N);
  }
}

// Round 4
// 539.032 us; speedup vs baseline: 2.0388x; 1.2180x over previous
//
#include <hip/hip_runtime.h>

typedef __bf16 bf16x8 __attribute__((ext_vector_type(8)));
typedef __bf16 bf16x2 __attribute__((ext_vector_type(2)));
typedef float f32x4 __attribute__((ext_vector_type(4)));

struct WPack { const float* p[9]; };

__device__ inline __bf16 f2bf(float f){ return (__bf16)f; }

// Convert 9 fp32 128x128 weight matrices into MFMA B-fragment layout (bf16).
// wf element index: m*16384 + c*2048 + ks*512 + lane*8 + j
//   holds W[k][col], k = ks*32 + (lane>>4)*8 + j, col = c*16 + (lane&15)
__global__ __launch_bounds__(256) void conv_w_kernel(WPack pk, __bf16* __restrict__ wf){
  int tid = blockIdx.x*256 + threadIdx.x;     // 9*16384 threads exactly
  int m = tid >> 14;
  int r = tid & 16383;
  int j = r & 7;
  int lane = (r >> 3) & 63;
  int ks = (r >> 9) & 3;
  int c = r >> 11;
  int k = ks*32 + ((lane>>4)<<3) + j;
  int col = (c<<4) + (lane & 15);
  wf[tid] = f2bf(pk.p[m][k*128 + col]);
}

// fp32 -> bf16 bulk convert, 8 elems/thread
__global__ __launch_bounds__(256) void f2b_kernel(const float* __restrict__ x, __bf16* __restrict__ xb, int n8){
  int i = blockIdx.x*256 + threadIdx.x;
  if (i >= n8) return;
  f32x4 a = ((const f32x4*)x)[2*i];
  f32x4 b = ((const f32x4*)x)[2*i+1];
  bf16x8 r;
  r[0]=f2bf(a[0]); r[1]=f2bf(a[1]); r[2]=f2bf(a[2]); r[3]=f2bf(a[3]);
  r[4]=f2bf(b[0]); r[5]=f2bf(b[1]); r[6]=f2bf(b[2]); r[7]=f2bf(b[3]);
  ((bf16x8*)xb)[i] = r;
}

// deg histogram + per-edge rank within its dst (captured from the same atomic)
__global__ __launch_bounds__(256) void hist_kernel(const int* __restrict__ ei, int E,
    int* __restrict__ deg, int* __restrict__ rank){
  int i = blockIdx.x*256 + threadIdx.x;
  if (i < E) rank[i] = atomicAdd(&deg[ei[E + i]], 1);   // dst row
}

// ---- 3-phase parallel exclusive scan of deg[N] -> rs[N] (+ rs[N]=total) ----
__global__ __launch_bounds__(256) void scan1_kernel(const int* __restrict__ deg, int* __restrict__ bsum, int N){
  __shared__ int sh[256];
  int b = blockIdx.x, t = threadIdx.x;
  int base = b*2048 + t*8;
  int s = 0;
  #pragma unroll
  for (int j = 0; j < 8; j++){ int i = base + j; if (i < N) s += deg[i]; }
  sh[t] = s; __syncthreads();
  for (int off = 128; off > 0; off >>= 1){
    if (t < off) sh[t] += sh[t + off];
    __syncthreads();
  }
  if (t == 0) bsum[b] = sh[0];
}

__global__ __launch_bounds__(256) void scan2_kernel(const int* __restrict__ bsum, int* __restrict__ boff,
                                                    int NB, int* __restrict__ rs_total){
  __shared__ int sh[256];
  int t = threadIdx.x;
  int v = (t < NB) ? bsum[t] : 0;
  sh[t] = v; __syncthreads();
  for (int off = 1; off < 256; off <<= 1){
    int u = (t >= off) ? sh[t - off] : 0;
    __syncthreads();
    sh[t] += u;
    __syncthreads();
  }
  if (t < NB) boff[t] = sh[t] - v;          // exclusive
  if (t == 255) *rs_total = sh[255];        // rs[N] = E
}

__global__ __launch_bounds__(256) void scan3_kernel(const int* __restrict__ deg, const int* __restrict__ boff,
                                                    int* __restrict__ rs, int N){
  __shared__ int sh[256];
  int b = blockIdx.x, t = threadIdx.x;
  int base = b*2048 + t*8;
  int loc[8]; int s = 0;
  #pragma unroll
  for (int j = 0; j < 8; j++){ int i = base + j; int d = (i < N) ? deg[i] : 0; loc[j] = d; s += d; }
  sh[t] = s; __syncthreads();
  for (int off = 1; off < 256; off <<= 1){
    int u = (t >= off) ? sh[t - off] : 0;
    __syncthreads();
    sh[t] += u;
    __syncthreads();
  }
  int excl = boff[b] + sh[t] - s;
  #pragma unroll
  for (int j = 0; j < 8; j++){ int i = base + j; if (i < N) rs[i] = excl; excl += loc[j]; }
}

// atomic-free scatter: slot = rs[dst] + rank (unique by construction)
__global__ __launch_bounds__(256) void fill_kernel(const int* __restrict__ ei, int E,
    const int* __restrict__ rs, const int* __restrict__ rank, int* __restrict__ csr){
  int i = blockIdx.x*256 + threadIdx.x;
  if (i < E){
    int s = ei[i];
    int d = ei[E + i];
    csr[rs[d] + rank[i]] = s;
  }
}

// h[i] = x[i] + sum_{j in N(i)} x[j]; one wave per node, bf16x2 (4B) per lane, fp32 accum.
__global__ __launch_bounds__(256) void agg_kernel(const __bf16* __restrict__ xb,
    const int* __restrict__ rs, const int* __restrict__ csr,
    __bf16* __restrict__ hb, int N)
{
  int node = blockIdx.x*4 + (threadIdx.x >> 6);
  if (node >= N) return;
  int lane = threadIdx.x & 63;
  int s = rs[node], e = rs[node+1];
  bf16x2 self = ((const bf16x2*)(xb + (long)node*128))[lane];
  float a0 = (float)self[0], a1 = (float)self[1];
  for (int base = s; base < e; base += 64){
    int idx = base + lane;
    int nb = (idx < e) ? csr[idx] : 0;
    int cnt = e - base; if (cnt > 64) cnt = 64;
    int t = 0;
    for (; t + 1 < cnt; t += 2){
      int s0 = __shfl(nb, t);
      int s1 = __shfl(nb, t+1);
      bf16x2 v0 = ((const bf16x2*)(xb + (long)s0*128))[lane];
      bf16x2 v1 = ((const bf16x2*)(xb + (long)s1*128))[lane];
      a0 += (float)v0[0] + (float)v1[0];
      a1 += (float)v0[1] + (float)v1[1];
    }
    if (t < cnt){
      int s0 = __shfl(nb, t);
      bf16x2 v0 = ((const bf16x2*)(xb + (long)s0*128))[lane];
      a0 += (float)v0[0];
      a1 += (float)v0[1];
    }
  }
  bf16x2 r; r[0] = f2bf(a0); r[1] = f2bf(a1);
  ((bf16x2*)(hb + (long)node*128))[lane] = r;
}

// C[M,128] = act(A[M,128] @ W + bias [+ res]), bf16 in/out, fp32 accum.
// Block: 256 thr = 4 waves; each wave owns a 32-col stripe, loops 8 row-tiles (128 rows/block).
// W held in registers as 8 B-fragments (loaded once). In-place A==out safe via per-tile barrier.
template<int ACT, bool RES>
__global__ __launch_bounds__(256) void gemm128(const __bf16* __restrict__ A,
    const __bf16* __restrict__ wf, const float* __restrict__ bias,
    const __bf16* __restrict__ res, __bf16* __restrict__ out, int M)
{
  int lane = threadIdx.x & 63;
  int wid = threadIdx.x >> 6;
  long row0 = (long)blockIdx.x * 128;
  const bf16x8* wfv = (const bf16x8*)wf;
  bf16x8 bv[2][4];
  #pragma unroll
  for (int c2 = 0; c2 < 2; c2++)
    #pragma unroll
    for (int ks = 0; ks < 4; ks++)
      bv[c2][ks] = wfv[((wid*2 + c2)*4 + ks)*64 + lane];
  int col0 = wid*32 + (lane & 15);
  float b0 = 0.f, b1 = 0.f;
  if (bias){ b0 = bias[col0]; b1 = bias[col0 + 16]; }
  int koff = (lane >> 4) << 3;
  #pragma unroll 1
  for (int rt = 0; rt < 8; rt++){
    long row = row0 + rt*16 + (lane & 15);
    long rowc = (row < M) ? row : (long)(M-1);
    const __bf16* ap = A + rowc*128 + koff;
    bf16x8 av[4];
    #pragma unroll
    for (int ks = 0; ks < 4; ks++)
      av[ks] = *(const bf16x8*)(ap + ks*32);
    __syncthreads();   // all waves' loads of this tile complete before any in-place write
    f32x4 acc0 = {0.f,0.f,0.f,0.f}, acc1 = {0.f,0.f,0.f,0.f};
    #pragma unroll
    for (int ks = 0; ks < 4; ks++){
      acc0 = __builtin_amdgcn_mfma_f32_16x16x32_bf16(av[ks], bv[0][ks], acc0, 0, 0, 0);
      acc1 = __builtin_amdgcn_mfma_f32_16x16x32_bf16(av[ks], bv[1][ks], acc1, 0, 0, 0);
    }
    long orow0 = row0 + rt*16 + ((lane >> 4) << 2);
    #pragma unroll
    for (int c2 = 0; c2 < 2; c2++){
      f32x4 acc = c2 ? acc1 : acc0;
      int col = col0 + c2*16;
      float bb = c2 ? b1 : b0;
      #pragma unroll
      for (int i = 0; i < 4; i++){
        long orow = orow0 + i;
        if (orow < M){
          long idx = orow*128 + col;
          float v = acc[i] + bb;
          if (RES) v += (float)res[idx];
          if (ACT == 1) v = fmaxf(v, 0.f);
          if (ACT == 2) v = (v > 0.f) ? v : (__expf(v) - 1.f);
          out[idx] = f2bf(v);
        }
      }
    }
  }
}

// out[M,128] = [y1|y2|y3] @ jkW + jkb   (K = 384, fp32 out, single pass)
__global__ __launch_bounds__(256) void jk_gemm(const __bf16* __restrict__ y1,
    const __bf16* __restrict__ y2, const __bf16* __restrict__ y3,
    const __bf16* __restrict__ wf, const float* __restrict__ bias,
    float* __restrict__ out, int M)
{
  int lane = threadIdx.x & 63;
  int wid = threadIdx.x >> 6;
  long row0 = (long)blockIdx.x * 128;
  const bf16x8* wfv = (const bf16x8*)wf;
  bf16x8 bv[2][12];
  #pragma unroll
  for (int c2 = 0; c2 < 2; c2++)
    #pragma unroll
    for (int ks = 0; ks < 12; ks++)
      bv[c2][ks] = wfv[(size_t)(6 + (ks>>2))*2048 + (size_t)((wid*2 + c2)*4 + (ks&3))*64 + lane];
  int col0 = wid*32 + (lane & 15);
  float b0 = bias[col0], b1 = bias[col0 + 16];
  int koff = (lane >> 4) << 3;
  const __bf16* ys[3] = {y1, y2, y3};
  #pragma unroll 1
  for (int rt = 0; rt < 8; rt++){
    long row = row0 + rt*16 + (lane & 15);
    long rowc = (row < M) ? row : (long)(M-1);
    f32x4 acc0 = {0.f,0.f,0.f,0.f}, acc1 = {0.f,0.f,0.f,0.f};
    #pragma unroll
    for (int ks = 0; ks < 12; ks++){
      bf16x8 av = *(const bf16x8*)(ys[ks>>2] + rowc*128 + (ks&3)*32 + koff);
      acc0 = __builtin_amdgcn_mfma_f32_16x16x32_bf16(av, bv[0][ks], acc0, 0, 0, 0);
      acc1 = __builtin_amdgcn_mfma_f32_16x16x32_bf16(av, bv[1][ks], acc1, 0, 0, 0);
    }
    long orow0 = row0 + rt*16 + ((lane >> 4) << 2);
    #pragma unroll
    for (int c2 = 0; c2 < 2; c2++){
      f32x4 acc = c2 ? acc1 : acc0;
      int col = col0 + c2*16;
      float bb = c2 ? b1 : b0;
      #pragma unroll
      for (int i = 0; i < 4; i++){
        long orow = orow0 + i;
        if (orow < M)
          out[orow*128 + col] = acc[i] + bb;
      }
    }
  }
}

extern "C" void kernel_launch(void* const* d_in, const int* in_sizes, int n_in,
                              void* d_out, int out_size, void* d_ws, size_t ws_size,
                              hipStream_t stream)
{
  const float* x   = (const float*)d_in[0];
  const int*   ei  = (const int*)d_in[1];
  const float* w1[3] = {(const float*)d_in[2], (const float*)d_in[6], (const float*)d_in[10]};
  const float* b1[3] = {(const float*)d_in[3], (const float*)d_in[7], (const float*)d_in[11]};
  const float* w2[3] = {(const float*)d_in[4], (const float*)d_in[8], (const float*)d_in[12]};
  const float* b2[3] = {(const float*)d_in[5], (const float*)d_in[9], (const float*)d_in[13]};
  const float* jkw = (const float*)d_in[14];
  const float* jkb = (const float*)d_in[15];
  int N = in_sizes[0] / 128;
  int E = in_sizes[1] / 2;
  float* outp = (float*)d_out;

  char* wptr = (char*)d_ws;
  auto alloc = [&](size_t bytes)->void*{
    void* p = (void*)wptr; wptr += (bytes + 255) & ~(size_t)255; return p;
  };
  int* deg  = (int*)alloc((size_t)N*4);
  int* rs   = (int*)alloc((size_t)(N+1)*4);
  int* rank = (int*)alloc((size_t)E*4);
  int* csr  = (int*)alloc((size_t)E*4);
  __bf16* y[4];
  for (int i = 0; i < 4; i++) y[i] = (__bf16*)alloc((size_t)N*128*2);
  __bf16* hb = (__bf16*)alloc((size_t)N*128*2);
  __bf16* wf = (__bf16*)alloc((size_t)9*16384*2);
  int nsb = (N + 2047) / 2048;                 // scan blocks (49 for N=100K)
  int* bsum = (int*)alloc((size_t)nsb*4);
  int* boff = (int*)alloc((size_t)nsb*4);

  hipMemsetAsync(deg, 0, (size_t)N*4, stream);

  WPack pk;
  pk.p[0] = w1[0]; pk.p[1] = w2[0];
  pk.p[2] = w1[1]; pk.p[3] = w2[1];
  pk.p[4] = w1[2]; pk.p[5] = w2[2];
  pk.p[6] = jkw; pk.p[7] = jkw + 16384; pk.p[8] = jkw + 32768;
  conv_w_kernel<<<576, 256, 0, stream>>>(pk, wf);

  f2b_kernel<<<(N*128/8 + 255)/256, 256, 0, stream>>>(x, y[0], N*128/8);

  hist_kernel<<<(E + 255)/256, 256, 0, stream>>>(ei, E, deg, rank);
  scan1_kernel<<<nsb, 256, 0, stream>>>(deg, bsum, N);
  scan2_kernel<<<1, 256, 0, stream>>>(bsum, boff, nsb, rs + N);
  scan3_kernel<<<nsb, 256, 0, stream>>>(deg, boff, rs, N);
  fill_kernel<<<(E + 255)/256, 256, 0, stream>>>(ei, E, rs, rank, csr);

  int gemm_blocks = (N + 127)/128;
  for (int l = 0; l < 3; l++){
    agg_kernel<<<(N + 3)/4, 256, 0, stream>>>(y[l], rs, csr, hb, N);
    // hb = relu(hb @ w1 + b1)  (in place, barrier-protected)
    gemm128<1,false><<<gemm_blocks, 256, 0, stream>>>(hb, wf + (size_t)(2*l)*16384, b1[l], nullptr, hb, N);
    // y[l+1] = [elu](hb @ w2 + b2 + y[l])
    if (l < 2)
      gemm128<2,true><<<gemm_blocks, 256, 0, stream>>>(hb, wf + (size_t)(2*l+1)*16384, b2[l], y[l], y[l+1], N);
    else
      gemm128<0,true><<<gemm_blocks, 256, 0, stream>>>(hb, wf + (size_t)(2*l+1)*16384, b2[l], y[l], y[l+1], N);
  }
  jk_gemm<<<gemm_blocks, 256, 0, stream>>>(y[1], y[2], y[3], wf, jkb, outp, N);
}

// Round 5
// 511.820 us; speedup vs baseline: 2.1472x; 1.0532x over previous
//
#include <hip/hip_runtime.h>

typedef __bf16 bf16x8 __attribute__((ext_vector_type(8)));
typedef __bf16 bf16x2 __attribute__((ext_vector_type(2)));
typedef float f32x4 __attribute__((ext_vector_type(4)));

struct WPack { const float* p[9]; };

__device__ inline __bf16 f2bf(float f){ return (__bf16)f; }

// Convert 9 fp32 128x128 weight matrices into MFMA B-fragment layout (bf16).
// wf element index: m*16384 + c*2048 + ks*512 + lane*8 + j
//   holds W[k][col], k = ks*32 + (lane>>4)*8 + j, col = c*16 + (lane&15)
__global__ __launch_bounds__(256) void conv_w_kernel(WPack pk, __bf16* __restrict__ wf){
  int tid = blockIdx.x*256 + threadIdx.x;     // 9*16384 threads exactly
  int m = tid >> 14;
  int r = tid & 16383;
  int j = r & 7;
  int lane = (r >> 3) & 63;
  int ks = (r >> 9) & 3;
  int c = r >> 11;
  int k = ks*32 + ((lane>>4)<<3) + j;
  int col = (c<<4) + (lane & 15);
  wf[tid] = f2bf(pk.p[m][k*128 + col]);
}

// fp32 -> bf16 bulk convert, 8 elems/thread
__global__ __launch_bounds__(256) void f2b_kernel(const float* __restrict__ x, __bf16* __restrict__ xb, int n8){
  int i = blockIdx.x*256 + threadIdx.x;
  if (i >= n8) return;
  f32x4 a = ((const f32x4*)x)[2*i];
  f32x4 b = ((const f32x4*)x)[2*i+1];
  bf16x8 r;
  r[0]=f2bf(a[0]); r[1]=f2bf(a[1]); r[2]=f2bf(a[2]); r[3]=f2bf(a[3]);
  r[4]=f2bf(b[0]); r[5]=f2bf(b[1]); r[6]=f2bf(b[2]); r[7]=f2bf(b[3]);
  ((bf16x8*)xb)[i] = r;
}

// deg histogram + per-edge rank within its dst (captured from the same atomic)
__global__ __launch_bounds__(256) void hist_kernel(const int* __restrict__ ei, int E,
    int* __restrict__ deg, int* __restrict__ rank){
  int i = blockIdx.x*256 + threadIdx.x;
  if (i < E) rank[i] = atomicAdd(&deg[ei[E + i]], 1);   // dst row
}

// ---- 3-phase parallel exclusive scan of deg[N] -> rs[N] (+ rs[N]=total) ----
__global__ __launch_bounds__(256) void scan1_kernel(const int* __restrict__ deg, int* __restrict__ bsum, int N){
  __shared__ int sh[256];
  int b = blockIdx.x, t = threadIdx.x;
  int base = b*2048 + t*8;
  int s = 0;
  #pragma unroll
  for (int j = 0; j < 8; j++){ int i = base + j; if (i < N) s += deg[i]; }
  sh[t] = s; __syncthreads();
  for (int off = 128; off > 0; off >>= 1){
    if (t < off) sh[t] += sh[t + off];
    __syncthreads();
  }
  if (t == 0) bsum[b] = sh[0];
}

__global__ __launch_bounds__(256) void scan2_kernel(const int* __restrict__ bsum, int* __restrict__ boff,
                                                    int NB, int* __restrict__ rs_total){
  __shared__ int sh[256];
  int t = threadIdx.x;
  int v = (t < NB) ? bsum[t] : 0;
  sh[t] = v; __syncthreads();
  for (int off = 1; off < 256; off <<= 1){
    int u = (t >= off) ? sh[t - off] : 0;
    __syncthreads();
    sh[t] += u;
    __syncthreads();
  }
  if (t < NB) boff[t] = sh[t] - v;          // exclusive
  if (t == 255) *rs_total = sh[255];        // rs[N] = E
}

__global__ __launch_bounds__(256) void scan3_kernel(const int* __restrict__ deg, const int* __restrict__ boff,
                                                    int* __restrict__ rs, int N){
  __shared__ int sh[256];
  int b = blockIdx.x, t = threadIdx.x;
  int base = b*2048 + t*8;
  int loc[8]; int s = 0;
  #pragma unroll
  for (int j = 0; j < 8; j++){ int i = base + j; int d = (i < N) ? deg[i] : 0; loc[j] = d; s += d; }
  sh[t] = s; __syncthreads();
  for (int off = 1; off < 256; off <<= 1){
    int u = (t >= off) ? sh[t - off] : 0;
    __syncthreads();
    sh[t] += u;
    __syncthreads();
  }
  int excl = boff[b] + sh[t] - s;
  #pragma unroll
  for (int j = 0; j < 8; j++){ int i = base + j; if (i < N) rs[i] = excl; excl += loc[j]; }
}

// atomic-free scatter: slot = rs[dst] + rank (unique by construction)
__global__ __launch_bounds__(256) void fill_kernel(const int* __restrict__ ei, int E,
    const int* __restrict__ rs, const int* __restrict__ rank, int* __restrict__ csr){
  int i = blockIdx.x*256 + threadIdx.x;
  if (i < E){
    int s = ei[i];
    int d = ei[E + i];
    csr[rs[d] + rank[i]] = s;
  }
}

// h[i] = x[i] + sum_{j in N(i)} x[j]
// One wave per node. 16 lanes per row (bf16x8 = 16B/lane), so each wave-load
// gathers 4 neighbor rows; unroll x2 = 8 rows in flight. fp32 accum; quad
// partials combined via shfl_xor(16,32); lanes 0-15 write the 256B row.
__global__ __launch_bounds__(256) void agg_kernel(const __bf16* __restrict__ xb,
    const int* __restrict__ rs, const int* __restrict__ csr,
    __bf16* __restrict__ hb, int N)
{
  int node = blockIdx.x*4 + (threadIdx.x >> 6);
  if (node >= N) return;
  int lane = threadIdx.x & 63;
  int quad = lane >> 4;       // which of 4 concurrent rows this lane serves
  int l16  = lane & 15;       // lane within row: dims [l16*8, l16*8+8)
  int s = rs[node], e = rs[node+1];
  float a[8] = {0.f,0.f,0.f,0.f,0.f,0.f,0.f,0.f};
  for (int base = s; base < e; base += 64){
    int idx = base + lane;
    int nb = (idx < e) ? csr[idx] : 0;
    int cnt = e - base; if (cnt > 64) cnt = 64;
    int t = 0;
    for (; t + 8 <= cnt; t += 8){
      int sA = __shfl(nb, t + quad);
      int sB = __shfl(nb, t + 4 + quad);
      bf16x8 vA = ((const bf16x8*)(xb + (long)sA*128))[l16];
      bf16x8 vB = ((const bf16x8*)(xb + (long)sB*128))[l16];
      #pragma unroll
      for (int j = 0; j < 8; j++) a[j] += (float)vA[j] + (float)vB[j];
    }
    for (; t < cnt; t += 4){
      int i = t + quad;
      int ic = (i < cnt) ? i : (cnt - 1);
      int sA = __shfl(nb, ic);
      bf16x8 vA = ((const bf16x8*)(xb + (long)sA*128))[l16];
      if (i < cnt){
        #pragma unroll
        for (int j = 0; j < 8; j++) a[j] += (float)vA[j];
      }
    }
  }
  if (quad == 0){  // self row
    bf16x8 sv = ((const bf16x8*)(xb + (long)node*128))[l16];
    #pragma unroll
    for (int j = 0; j < 8; j++) a[j] += (float)sv[j];
  }
  #pragma unroll
  for (int j = 0; j < 8; j++){
    a[j] += __shfl_xor(a[j], 16);
    a[j] += __shfl_xor(a[j], 32);
  }
  if (quad == 0){
    bf16x8 r;
    #pragma unroll
    for (int j = 0; j < 8; j++) r[j] = f2bf(a[j]);
    ((bf16x8*)(hb + (long)node*128))[l16] = r;
  }
}

// C[M,128] = act(A[M,128] @ W + bias [+ res]), bf16 in/out, fp32 accum.
// Block: 256 thr = 4 waves; each wave owns a 32-col stripe, loops 8 row-tiles (128 rows/block).
// W held in registers as 8 B-fragments (loaded once). In-place A==out safe via per-tile barrier.
template<int ACT, bool RES>
__global__ __launch_bounds__(256) void gemm128(const __bf16* __restrict__ A,
    const __bf16* __restrict__ wf, const float* __restrict__ bias,
    const __bf16* __restrict__ res, __bf16* __restrict__ out, int M)
{
  int lane = threadIdx.x & 63;
  int wid = threadIdx.x >> 6;
  long row0 = (long)blockIdx.x * 128;
  const bf16x8* wfv = (const bf16x8*)wf;
  bf16x8 bv[2][4];
  #pragma unroll
  for (int c2 = 0; c2 < 2; c2++)
    #pragma unroll
    for (int ks = 0; ks < 4; ks++)
      bv[c2][ks] = wfv[((wid*2 + c2)*4 + ks)*64 + lane];
  int col0 = wid*32 + (lane & 15);
  float b0 = 0.f, b1 = 0.f;
  if (bias){ b0 = bias[col0]; b1 = bias[col0 + 16]; }
  int koff = (lane >> 4) << 3;
  #pragma unroll 1
  for (int rt = 0; rt < 8; rt++){
    long row = row0 + rt*16 + (lane & 15);
    long rowc = (row < M) ? row : (long)(M-1);
    const __bf16* ap = A + rowc*128 + koff;
    bf16x8 av[4];
    #pragma unroll
    for (int ks = 0; ks < 4; ks++)
      av[ks] = *(const bf16x8*)(ap + ks*32);
    __syncthreads();   // all waves' loads of this tile complete before any in-place write
    f32x4 acc0 = {0.f,0.f,0.f,0.f}, acc1 = {0.f,0.f,0.f,0.f};
    #pragma unroll
    for (int ks = 0; ks < 4; ks++){
      acc0 = __builtin_amdgcn_mfma_f32_16x16x32_bf16(av[ks], bv[0][ks], acc0, 0, 0, 0);
      acc1 = __builtin_amdgcn_mfma_f32_16x16x32_bf16(av[ks], bv[1][ks], acc1, 0, 0, 0);
    }
    long orow0 = row0 + rt*16 + ((lane >> 4) << 2);
    #pragma unroll
    for (int c2 = 0; c2 < 2; c2++){
      f32x4 acc = c2 ? acc1 : acc0;
      int col = col0 + c2*16;
      float bb = c2 ? b1 : b0;
      #pragma unroll
      for (int i = 0; i < 4; i++){
        long orow = orow0 + i;
        if (orow < M){
          long idx = orow*128 + col;
          float v = acc[i] + bb;
          if (RES) v += (float)res[idx];
          if (ACT == 1) v = fmaxf(v, 0.f);
          if (ACT == 2) v = (v > 0.f) ? v : (__expf(v) - 1.f);
          out[idx] = f2bf(v);
        }
      }
    }
  }
}

// out[M,128] = [y1|y2|y3] @ jkW + jkb   (K = 384, fp32 out, single pass)
__global__ __launch_bounds__(256) void jk_gemm(const __bf16* __restrict__ y1,
    const __bf16* __restrict__ y2, const __bf16* __restrict__ y3,
    const __bf16* __restrict__ wf, const float* __restrict__ bias,
    float* __restrict__ out, int M)
{
  int lane = threadIdx.x & 63;
  int wid = threadIdx.x >> 6;
  long row0 = (long)blockIdx.x * 128;
  const bf16x8* wfv = (const bf16x8*)wf;
  bf16x8 bv[2][12];
  #pragma unroll
  for (int c2 = 0; c2 < 2; c2++)
    #pragma unroll
    for (int ks = 0; ks < 12; ks++)
      bv[c2][ks] = wfv[(size_t)(6 + (ks>>2))*2048 + (size_t)((wid*2 + c2)*4 + (ks&3))*64 + lane];
  int col0 = wid*32 + (lane & 15);
  float b0 = bias[col0], b1 = bias[col0 + 16];
  int koff = (lane >> 4) << 3;
  const __bf16* ys[3] = {y1, y2, y3};
  #pragma unroll 1
  for (int rt = 0; rt < 8; rt++){
    long row = row0 + rt*16 + (lane & 15);
    long rowc = (row < M) ? row : (long)(M-1);
    f32x4 acc0 = {0.f,0.f,0.f,0.f}, acc1 = {0.f,0.f,0.f,0.f};
    #pragma unroll
    for (int ks = 0; ks < 12; ks++){
      bf16x8 av = *(const bf16x8*)(ys[ks>>2] + rowc*128 + (ks&3)*32 + koff);
      acc0 = __builtin_amdgcn_mfma_f32_16x16x32_bf16(av, bv[0][ks], acc0, 0, 0, 0);
      acc1 = __builtin_amdgcn_mfma_f32_16x16x32_bf16(av, bv[1][ks], acc1, 0, 0, 0);
    }
    long orow0 = row0 + rt*16 + ((lane >> 4) << 2);
    #pragma unroll
    for (int c2 = 0; c2 < 2; c2++){
      f32x4 acc = c2 ? acc1 : acc0;
      int col = col0 + c2*16;
      float bb = c2 ? b1 : b0;
      #pragma unroll
      for (int i = 0; i < 4; i++){
        long orow = orow0 + i;
        if (orow < M)
          out[orow*128 + col] = acc[i] + bb;
      }
    }
  }
}

extern "C" void kernel_launch(void* const* d_in, const int* in_sizes, int n_in,
                              void* d_out, int out_size, void* d_ws, size_t ws_size,
                              hipStream_t stream)
{
  const float* x   = (const float*)d_in[0];
  const int*   ei  = (const int*)d_in[1];
  const float* w1[3] = {(const float*)d_in[2], (const float*)d_in[6], (const float*)d_in[10]};
  const float* b1[3] = {(const float*)d_in[3], (const float*)d_in[7], (const float*)d_in[11]};
  const float* w2[3] = {(const float*)d_in[4], (const float*)d_in[8], (const float*)d_in[12]};
  const float* b2[3] = {(const float*)d_in[5], (const float*)d_in[9], (const float*)d_in[13]};
  const float* jkw = (const float*)d_in[14];
  const float* jkb = (const float*)d_in[15];
  int N = in_sizes[0] / 128;
  int E = in_sizes[1] / 2;
  float* outp = (float*)d_out;

  char* wptr = (char*)d_ws;
  auto alloc = [&](size_t bytes)->void*{
    void* p = (void*)wptr; wptr += (bytes + 255) & ~(size_t)255; return p;
  };
  int* deg  = (int*)alloc((size_t)N*4);
  int* rs   = (int*)alloc((size_t)(N+1)*4);
  int* rank = (int*)alloc((size_t)E*4);
  int* csr  = (int*)alloc((size_t)E*4);
  __bf16* y[4];
  for (int i = 0; i < 4; i++) y[i] = (__bf16*)alloc((size_t)N*128*2);
  __bf16* hb = (__bf16*)alloc((size_t)N*128*2);
  __bf16* wf = (__bf16*)alloc((size_t)9*16384*2);
  int nsb = (N + 2047) / 2048;                 // scan blocks (49 for N=100K)
  int* bsum = (int*)alloc((size_t)nsb*4);
  int* boff = (int*)alloc((size_t)nsb*4);

  hipMemsetAsync(deg, 0, (size_t)N*4, stream);

  WPack pk;
  pk.p[0] = w1[0]; pk.p[1] = w2[0];
  pk.p[2] = w1[1]; pk.p[3] = w2[1];
  pk.p[4] = w1[2]; pk.p[5] = w2[2];
  pk.p[6] = jkw; pk.p[7] = jkw + 16384; pk.p[8] = jkw + 32768;
  conv_w_kernel<<<576, 256, 0, stream>>>(pk, wf);

  f2b_kernel<<<(N*128/8 + 255)/256, 256, 0, stream>>>(x, y[0], N*128/8);

  hist_kernel<<<(E + 255)/256, 256, 0, stream>>>(ei, E, deg, rank);
  scan1_kernel<<<nsb, 256, 0, stream>>>(deg, bsum, N);
  scan2_kernel<<<1, 256, 0, stream>>>(bsum, boff, nsb, rs + N);
  scan3_kernel<<<nsb, 256, 0, stream>>>(deg, boff, rs, N);
  fill_kernel<<<(E + 255)/256, 256, 0, stream>>>(ei, E, rs, rank, csr);

  int gemm_blocks = (N + 127)/128;
  for (int l = 0; l < 3; l++){
    agg_kernel<<<(N + 3)/4, 256, 0, stream>>>(y[l], rs, csr, hb, N);
    // hb = relu(hb @ w1 + b1)  (in place, barrier-protected)
    gemm128<1,false><<<gemm_blocks, 256, 0, stream>>>(hb, wf + (size_t)(2*l)*16384, b1[l], nullptr, hb, N);
    // y[l+1] = [elu](hb @ w2 + b2 + y[l])
    if (l < 2)
      gemm128<2,true><<<gemm_blocks, 256, 0, stream>>>(hb, wf + (size_t)(2*l+1)*16384, b2[l], y[l], y[l+1], N);
    else
      gemm128<0,true><<<gemm_blocks, 256, 0, stream>>>(hb, wf + (size_t)(2*l+1)*16384, b2[l], y[l], y[l+1], N);
  }
  jk_gemm<<<gemm_blocks, 256, 0, stream>>>(y[1], y[2], y[3], wf, jkb, outp, N);
}

// Round 6
// 465.846 us; speedup vs baseline: 2.3591x; 1.0987x over previous
//
#include <hip/hip_runtime.h>

typedef __bf16 bf16x8 __attribute__((ext_vector_type(8)));
typedef float f32x4 __attribute__((ext_vector_type(4)));

#define CHUNK 4096
#define NBUCK 512

struct WPack { const float* p[9]; };

__device__ inline __bf16 f2bf(float f){ return (__bf16)f; }

// Convert 9 fp32 128x128 weight matrices into MFMA B-fragment layout (bf16).
// wf element index: m*16384 + c*2048 + ks*512 + lane*8 + j
//   holds W[k][col], k = ks*32 + (lane>>4)*8 + j, col = c*16 + (lane&15)
__global__ __launch_bounds__(256) void conv_w_kernel(WPack pk, __bf16* __restrict__ wf){
  int tid = blockIdx.x*256 + threadIdx.x;     // 9*16384 threads exactly
  int m = tid >> 14;
  int r = tid & 16383;
  int j = r & 7;
  int lane = (r >> 3) & 63;
  int ks = (r >> 9) & 3;
  int c = r >> 11;
  int k = ks*32 + ((lane>>4)<<3) + j;
  int col = (c<<4) + (lane & 15);
  wf[tid] = f2bf(pk.p[m][k*128 + col]);
}

// fp32 -> bf16 bulk convert, 8 elems/thread
__global__ __launch_bounds__(256) void f2b_kernel(const float* __restrict__ x, __bf16* __restrict__ xb, int n8){
  int i = blockIdx.x*256 + threadIdx.x;
  if (i >= n8) return;
  f32x4 a = ((const f32x4*)x)[2*i];
  f32x4 b = ((const f32x4*)x)[2*i+1];
  bf16x8 r;
  r[0]=f2bf(a[0]); r[1]=f2bf(a[1]); r[2]=f2bf(a[2]); r[3]=f2bf(a[3]);
  r[4]=f2bf(b[0]); r[5]=f2bf(b[1]); r[6]=f2bf(b[2]); r[7]=f2bf(b[3]);
  ((bf16x8*)xb)[i] = r;
}

// ---- CSR build via two-level bucket sort (no global atomics) ----
// P1: per-block LDS histogram over 512 buckets (dst>>8); cnt[q*NBLK + b]
__global__ __launch_bounds__(256) void p1_count(const int* __restrict__ ei, int E, int NBLK,
    int* __restrict__ cnt){
  __shared__ int h[NBUCK];
  int b = blockIdx.x, t = threadIdx.x;
  h[t] = 0; h[t + 256] = 0;
  __syncthreads();
  int base = b*CHUNK;
  int lim = E - base; if (lim > CHUNK) lim = CHUNK;
  for (int i = t; i < lim; i += 256)
    atomicAdd(&h[ei[E + base + i] >> 8], 1);     // dst row
  __syncthreads();
  cnt[t*NBLK + b] = h[t];
  cnt[(t + 256)*NBLK + b] = h[t + 256];
}

// ---- 3-phase parallel exclusive scan of cnt[L] -> off[L] (+ total) ----
__global__ __launch_bounds__(256) void scan1_kernel(const int* __restrict__ cnt, int* __restrict__ bsum, int L){
  __shared__ int sh[256];
  int b = blockIdx.x, t = threadIdx.x;
  int base = b*2048 + t*8;
  int s = 0;
  #pragma unroll
  for (int j = 0; j < 8; j++){ int i = base + j; if (i < L) s += cnt[i]; }
  sh[t] = s; __syncthreads();
  for (int off = 128; off > 0; off >>= 1){
    if (t < off) sh[t] += sh[t + off];
    __syncthreads();
  }
  if (t == 0) bsum[b] = sh[0];
}

__global__ __launch_bounds__(256) void scan2_kernel(const int* __restrict__ bsum, int* __restrict__ boff,
                                                    int NB, int* __restrict__ total_out){
  __shared__ int sh[256];
  int t = threadIdx.x;
  int v = (t < NB) ? bsum[t] : 0;
  sh[t] = v; __syncthreads();
  for (int off = 1; off < 256; off <<= 1){
    int u = (t >= off) ? sh[t - off] : 0;
    __syncthreads();
    sh[t] += u;
    __syncthreads();
  }
  if (t < NB) boff[t] = sh[t] - v;          // exclusive
  if (t == 255) *total_out = sh[255];       // rs[N] = E
}

__global__ __launch_bounds__(256) void scan3_kernel(const int* __restrict__ cnt, const int* __restrict__ boff,
                                                    int* __restrict__ off, int L){
  __shared__ int sh[256];
  int b = blockIdx.x, t = threadIdx.x;
  int base = b*2048 + t*8;
  int loc[8]; int s = 0;
  #pragma unroll
  for (int j = 0; j < 8; j++){ int i = base + j; int d = (i < L) ? cnt[i] : 0; loc[j] = d; s += d; }
  sh[t] = s; __syncthreads();
  for (int o = 1; o < 256; o <<= 1){
    int u = (t >= o) ? sh[t - o] : 0;
    __syncthreads();
    sh[t] += u;
    __syncthreads();
  }
  int excl = boff[b] + sh[t] - s;
  #pragma unroll
  for (int j = 0; j < 8; j++){ int i = base + j; if (i < L) off[i] = excl; excl += loc[j]; }
}

// P3: scatter packed (src<<8 | dst&255) into bucket-sorted order via LDS cursors
__global__ __launch_bounds__(256) void p3_scatter(const int* __restrict__ ei, int E, int NBLK,
    const int* __restrict__ off, int* __restrict__ tpack){
  __shared__ int cur[NBUCK];
  int b = blockIdx.x, t = threadIdx.x;
  cur[t]       = off[t*NBLK + b];
  cur[t + 256] = off[(t + 256)*NBLK + b];
  __syncthreads();
  int base = b*CHUNK;
  int lim = E - base; if (lim > CHUNK) lim = CHUNK;
  for (int i = t; i < lim; i += 256){
    int s = ei[base + i];
    int d = ei[E + base + i];
    int p = atomicAdd(&cur[d >> 8], 1);   // LDS atomic: global slot
    tpack[p] = (s << 8) | (d & 255);
  }
}

// P4: one block per bucket (256 consecutive dsts). Exact LDS histogram + scan
// -> rs slice (coalesced) + csr slice (bucket-local scatter).
__global__ __launch_bounds__(256) void p4_build(const int* __restrict__ tpack,
    const int* __restrict__ off, int NBLK, int E, int N,
    int* __restrict__ rs, int* __restrict__ csr){
  __shared__ int dc[256], sc[256];
  int q = blockIdx.x, t = threadIdx.x;
  int bstart = off[q*NBLK];
  int bend = (q == NBUCK-1) ? E : off[(q+1)*NBLK];
  dc[t] = 0;
  __syncthreads();
  for (int i = bstart + t; i < bend; i += 256)
    atomicAdd(&dc[tpack[i] & 255], 1);
  __syncthreads();
  int v = dc[t];
  sc[t] = v; __syncthreads();
  for (int o = 1; o < 256; o <<= 1){
    int u = (t >= o) ? sc[t - o] : 0;
    __syncthreads();
    sc[t] += u;
    __syncthreads();
  }
  int ex = sc[t] - v;                  // exclusive within bucket
  int gd = q*256 + t;
  if (gd < N) rs[gd] = bstart + ex;
  __syncthreads();
  dc[t] = ex;                          // reuse as cursor
  __syncthreads();
  for (int i = bstart + t; i < bend; i += 256){
    int p = tpack[i];
    int r = atomicAdd(&dc[p & 255], 1);
    csr[bstart + r] = p >> 8;
  }
}

// h[i] = x[i] + sum_{j in N(i)} x[j]
// One wave per node. 16 lanes per row (bf16x8 = 16B/lane), so each wave-load
// gathers 4 neighbor rows; unroll x2 = 8 rows in flight. fp32 accum; quad
// partials combined via shfl_xor(16,32); lanes 0-15 write the 256B row.
__global__ __launch_bounds__(256) void agg_kernel(const __bf16* __restrict__ xb,
    const int* __restrict__ rs, const int* __restrict__ csr,
    __bf16* __restrict__ hb, int N)
{
  int node = blockIdx.x*4 + (threadIdx.x >> 6);
  if (node >= N) return;
  int lane = threadIdx.x & 63;
  int quad = lane >> 4;
  int l16  = lane & 15;
  int s = rs[node], e = rs[node+1];
  float a[8] = {0.f,0.f,0.f,0.f,0.f,0.f,0.f,0.f};
  for (int base = s; base < e; base += 64){
    int idx = base + lane;
    int nb = (idx < e) ? csr[idx] : 0;
    int cnt = e - base; if (cnt > 64) cnt = 64;
    int t = 0;
    for (; t + 8 <= cnt; t += 8){
      int sA = __shfl(nb, t + quad);
      int sB = __shfl(nb, t + 4 + quad);
      bf16x8 vA = ((const bf16x8*)(xb + (long)sA*128))[l16];
      bf16x8 vB = ((const bf16x8*)(xb + (long)sB*128))[l16];
      #pragma unroll
      for (int j = 0; j < 8; j++) a[j] += (float)vA[j] + (float)vB[j];
    }
    for (; t < cnt; t += 4){
      int i = t + quad;
      int ic = (i < cnt) ? i : (cnt - 1);
      int sA = __shfl(nb, ic);
      bf16x8 vA = ((const bf16x8*)(xb + (long)sA*128))[l16];
      if (i < cnt){
        #pragma unroll
        for (int j = 0; j < 8; j++) a[j] += (float)vA[j];
      }
    }
  }
  if (quad == 0){
    bf16x8 sv = ((const bf16x8*)(xb + (long)node*128))[l16];
    #pragma unroll
    for (int j = 0; j < 8; j++) a[j] += (float)sv[j];
  }
  #pragma unroll
  for (int j = 0; j < 8; j++){
    a[j] += __shfl_xor(a[j], 16);
    a[j] += __shfl_xor(a[j], 32);
  }
  if (quad == 0){
    bf16x8 r;
    #pragma unroll
    for (int j = 0; j < 8; j++) r[j] = f2bf(a[j]);
    ((bf16x8*)(hb + (long)node*128))[l16] = r;
  }
}

// C[M,128] = act(A[M,128] @ W + bias [+ res]), bf16 in/out, fp32 accum.
template<int ACT, bool RES>
__global__ __launch_bounds__(256) void gemm128(const __bf16* __restrict__ A,
    const __bf16* __restrict__ wf, const float* __restrict__ bias,
    const __bf16* __restrict__ res, __bf16* __restrict__ out, int M)
{
  int lane = threadIdx.x & 63;
  int wid = threadIdx.x >> 6;
  long row0 = (long)blockIdx.x * 128;
  const bf16x8* wfv = (const bf16x8*)wf;
  bf16x8 bv[2][4];
  #pragma unroll
  for (int c2 = 0; c2 < 2; c2++)
    #pragma unroll
    for (int ks = 0; ks < 4; ks++)
      bv[c2][ks] = wfv[((wid*2 + c2)*4 + ks)*64 + lane];
  int col0 = wid*32 + (lane & 15);
  float b0 = 0.f, b1 = 0.f;
  if (bias){ b0 = bias[col0]; b1 = bias[col0 + 16]; }
  int koff = (lane >> 4) << 3;
  #pragma unroll 1
  for (int rt = 0; rt < 8; rt++){
    long row = row0 + rt*16 + (lane & 15);
    long rowc = (row < M) ? row : (long)(M-1);
    const __bf16* ap = A + rowc*128 + koff;
    bf16x8 av[4];
    #pragma unroll
    for (int ks = 0; ks < 4; ks++)
      av[ks] = *(const bf16x8*)(ap + ks*32);
    __syncthreads();   // all waves' loads of this tile complete before any in-place write
    f32x4 acc0 = {0.f,0.f,0.f,0.f}, acc1 = {0.f,0.f,0.f,0.f};
    #pragma unroll
    for (int ks = 0; ks < 4; ks++){
      acc0 = __builtin_amdgcn_mfma_f32_16x16x32_bf16(av[ks], bv[0][ks], acc0, 0, 0, 0);
      acc1 = __builtin_amdgcn_mfma_f32_16x16x32_bf16(av[ks], bv[1][ks], acc1, 0, 0, 0);
    }
    long orow0 = row0 + rt*16 + ((lane >> 4) << 2);
    #pragma unroll
    for (int c2 = 0; c2 < 2; c2++){
      f32x4 acc = c2 ? acc1 : acc0;
      int col = col0 + c2*16;
      float bb = c2 ? b1 : b0;
      #pragma unroll
      for (int i = 0; i < 4; i++){
        long orow = orow0 + i;
        if (orow < M){
          long idx = orow*128 + col;
          float v = acc[i] + bb;
          if (RES) v += (float)res[idx];
          if (ACT == 1) v = fmaxf(v, 0.f);
          if (ACT == 2) v = (v > 0.f) ? v : (__expf(v) - 1.f);
          out[idx] = f2bf(v);
        }
      }
    }
  }
}

// out[M,128] = [y1|y2|y3] @ jkW + jkb   (K = 384, fp32 out, single pass)
__global__ __launch_bounds__(256) void jk_gemm(const __bf16* __restrict__ y1,
    const __bf16* __restrict__ y2, const __bf16* __restrict__ y3,
    const __bf16* __restrict__ wf, const float* __restrict__ bias,
    float* __restrict__ out, int M)
{
  int lane = threadIdx.x & 63;
  int wid = threadIdx.x >> 6;
  long row0 = (long)blockIdx.x * 128;
  const bf16x8* wfv = (const bf16x8*)wf;
  bf16x8 bv[2][12];
  #pragma unroll
  for (int c2 = 0; c2 < 2; c2++)
    #pragma unroll
    for (int ks = 0; ks < 12; ks++)
      bv[c2][ks] = wfv[(size_t)(6 + (ks>>2))*2048 + (size_t)((wid*2 + c2)*4 + (ks&3))*64 + lane];
  int col0 = wid*32 + (lane & 15);
  float b0 = bias[col0], b1 = bias[col0 + 16];
  int koff = (lane >> 4) << 3;
  const __bf16* ys[3] = {y1, y2, y3};
  #pragma unroll 1
  for (int rt = 0; rt < 8; rt++){
    long row = row0 + rt*16 + (lane & 15);
    long rowc = (row < M) ? row : (long)(M-1);
    f32x4 acc0 = {0.f,0.f,0.f,0.f}, acc1 = {0.f,0.f,0.f,0.f};
    #pragma unroll
    for (int ks = 0; ks < 12; ks++){
      bf16x8 av = *(const bf16x8*)(ys[ks>>2] + rowc*128 + (ks&3)*32 + koff);
      acc0 = __builtin_amdgcn_mfma_f32_16x16x32_bf16(av, bv[0][ks], acc0, 0, 0, 0);
      acc1 = __builtin_amdgcn_mfma_f32_16x16x32_bf16(av, bv[1][ks], acc1, 0, 0, 0);
    }
    long orow0 = row0 + rt*16 + ((lane >> 4) << 2);
    #pragma unroll
    for (int c2 = 0; c2 < 2; c2++){
      f32x4 acc = c2 ? acc1 : acc0;
      int col = col0 + c2*16;
      float bb = c2 ? b1 : b0;
      #pragma unroll
      for (int i = 0; i < 4; i++){
        long orow = orow0 + i;
        if (orow < M)
          out[orow*128 + col] = acc[i] + bb;
      }
    }
  }
}

extern "C" void kernel_launch(void* const* d_in, const int* in_sizes, int n_in,
                              void* d_out, int out_size, void* d_ws, size_t ws_size,
                              hipStream_t stream)
{
  const float* x   = (const float*)d_in[0];
  const int*   ei  = (const int*)d_in[1];
  const float* w1[3] = {(const float*)d_in[2], (const float*)d_in[6], (const float*)d_in[10]};
  const float* b1[3] = {(const float*)d_in[3], (const float*)d_in[7], (const float*)d_in[11]};
  const float* w2[3] = {(const float*)d_in[4], (const float*)d_in[8], (const float*)d_in[12]};
  const float* b2[3] = {(const float*)d_in[5], (const float*)d_in[9], (const float*)d_in[13]};
  const float* jkw = (const float*)d_in[14];
  const float* jkb = (const float*)d_in[15];
  int N = in_sizes[0] / 128;
  int E = in_sizes[1] / 2;
  float* outp = (float*)d_out;

  char* wptr = (char*)d_ws;
  auto alloc = [&](size_t bytes)->void*{
    void* p = (void*)wptr; wptr += (bytes + 255) & ~(size_t)255; return p;
  };
  int NBLK = (E + CHUNK - 1) / CHUNK;          // 391
  int L = NBUCK * NBLK;                        // 200K
  int* rs    = (int*)alloc((size_t)(N+1)*4);
  int* csr   = (int*)alloc((size_t)E*4);
  int* tpack = (int*)alloc((size_t)E*4);
  int* cnt   = (int*)alloc((size_t)L*4);
  int* off   = (int*)alloc((size_t)L*4);
  __bf16* y[4];
  for (int i = 0; i < 4; i++) y[i] = (__bf16*)alloc((size_t)N*128*2);
  __bf16* hb = (__bf16*)alloc((size_t)N*128*2);
  __bf16* wf = (__bf16*)alloc((size_t)9*16384*2);
  int nsb = (L + 2047) / 2048;                 // scan blocks (98)
  int* bsum = (int*)alloc((size_t)nsb*4);
  int* boff = (int*)alloc((size_t)nsb*4);

  WPack pk;
  pk.p[0] = w1[0]; pk.p[1] = w2[0];
  pk.p[2] = w1[1]; pk.p[3] = w2[1];
  pk.p[4] = w1[2]; pk.p[5] = w2[2];
  pk.p[6] = jkw; pk.p[7] = jkw + 16384; pk.p[8] = jkw + 32768;
  conv_w_kernel<<<576, 256, 0, stream>>>(pk, wf);

  f2b_kernel<<<(N*128/8 + 255)/256, 256, 0, stream>>>(x, y[0], N*128/8);

  p1_count<<<NBLK, 256, 0, stream>>>(ei, E, NBLK, cnt);
  scan1_kernel<<<nsb, 256, 0, stream>>>(cnt, bsum, L);
  scan2_kernel<<<1, 256, 0, stream>>>(bsum, boff, nsb, rs + N);   // rs[N] = E
  scan3_kernel<<<nsb, 256, 0, stream>>>(cnt, boff, off, L);
  p3_scatter<<<NBLK, 256, 0, stream>>>(ei, E, NBLK, off, tpack);
  p4_build<<<NBUCK, 256, 0, stream>>>(tpack, off, NBLK, E, N, rs, csr);

  int gemm_blocks = (N + 127)/128;
  for (int l = 0; l < 3; l++){
    agg_kernel<<<(N + 3)/4, 256, 0, stream>>>(y[l], rs, csr, hb, N);
    gemm128<1,false><<<gemm_blocks, 256, 0, stream>>>(hb, wf + (size_t)(2*l)*16384, b1[l], nullptr, hb, N);
    if (l < 2)
      gemm128<2,true><<<gemm_blocks, 256, 0, stream>>>(hb, wf + (size_t)(2*l+1)*16384, b2[l], y[l], y[l+1], N);
    else
      gemm128<0,true><<<gemm_blocks, 256, 0, stream>>>(hb, wf + (size_t)(2*l+1)*16384, b2[l], y[l], y[l+1], N);
  }
  jk_gemm<<<gemm_blocks, 256, 0, stream>>>(y[1], y[2], y[3], wf, jkb, outp, N);
}

// Round 7
// 428.604 us; speedup vs baseline: 2.5641x; 1.0869x over previous
//
#include <hip/hip_runtime.h>

typedef __bf16 bf16x8 __attribute__((ext_vector_type(8)));
typedef float f32x4 __attribute__((ext_vector_type(4)));

#define CHUNK 4096
#define NBUCK 512

struct WPack { const float* p[9]; };

__device__ inline __bf16 f2bf(float f){ return (__bf16)f; }

// Convert 9 fp32 128x128 weight matrices into MFMA B-fragment layout (bf16).
// wf element index: m*16384 + c*2048 + ks*512 + lane*8 + j
//   holds W[k][col], k = ks*32 + (lane>>4)*8 + j, col = c*16 + (lane&15)
__global__ __launch_bounds__(256) void conv_w_kernel(WPack pk, __bf16* __restrict__ wf){
  int tid = blockIdx.x*256 + threadIdx.x;     // 9*16384 threads exactly
  int m = tid >> 14;
  int r = tid & 16383;
  int j = r & 7;
  int lane = (r >> 3) & 63;
  int ks = (r >> 9) & 3;
  int c = r >> 11;
  int k = ks*32 + ((lane>>4)<<3) + j;
  int col = (c<<4) + (lane & 15);
  wf[tid] = f2bf(pk.p[m][k*128 + col]);
}

// fp32 -> bf16 bulk convert, 8 elems/thread
__global__ __launch_bounds__(256) void f2b_kernel(const float* __restrict__ x, __bf16* __restrict__ xb, int n8){
  int i = blockIdx.x*256 + threadIdx.x;
  if (i >= n8) return;
  f32x4 a = ((const f32x4*)x)[2*i];
  f32x4 b = ((const f32x4*)x)[2*i+1];
  bf16x8 r;
  r[0]=f2bf(a[0]); r[1]=f2bf(a[1]); r[2]=f2bf(a[2]); r[3]=f2bf(a[3]);
  r[4]=f2bf(b[0]); r[5]=f2bf(b[1]); r[6]=f2bf(b[2]); r[7]=f2bf(b[3]);
  ((bf16x8*)xb)[i] = r;
}

// ---- CSR build via two-level bucket sort (no global atomics) ----
// P1: per-block LDS histogram over 512 buckets (dst>>8); cnt[q*NBLK + b]
__global__ __launch_bounds__(256) void p1_count(const int* __restrict__ ei, int E, int NBLK,
    int* __restrict__ cnt){
  __shared__ int h[NBUCK];
  int b = blockIdx.x, t = threadIdx.x;
  h[t] = 0; h[t + 256] = 0;
  __syncthreads();
  int base = b*CHUNK;
  int lim = E - base; if (lim > CHUNK) lim = CHUNK;
  for (int i = t; i < lim; i += 256)
    atomicAdd(&h[ei[E + base + i] >> 8], 1);     // dst row
  __syncthreads();
  cnt[t*NBLK + b] = h[t];
  cnt[(t + 256)*NBLK + b] = h[t + 256];
}

// ---- 3-phase parallel exclusive scan of cnt[L] -> off[L] (+ total) ----
__global__ __launch_bounds__(256) void scan1_kernel(const int* __restrict__ cnt, int* __restrict__ bsum, int L){
  __shared__ int sh[256];
  int b = blockIdx.x, t = threadIdx.x;
  int base = b*2048 + t*8;
  int s = 0;
  #pragma unroll
  for (int j = 0; j < 8; j++){ int i = base + j; if (i < L) s += cnt[i]; }
  sh[t] = s; __syncthreads();
  for (int off = 128; off > 0; off >>= 1){
    if (t < off) sh[t] += sh[t + off];
    __syncthreads();
  }
  if (t == 0) bsum[b] = sh[0];
}

__global__ __launch_bounds__(256) void scan2_kernel(const int* __restrict__ bsum, int* __restrict__ boff,
                                                    int NB, int* __restrict__ total_out){
  __shared__ int sh[256];
  int t = threadIdx.x;
  int v = (t < NB) ? bsum[t] : 0;
  sh[t] = v; __syncthreads();
  for (int off = 1; off < 256; off <<= 1){
    int u = (t >= off) ? sh[t - off] : 0;
    __syncthreads();
    sh[t] += u;
    __syncthreads();
  }
  if (t < NB) boff[t] = sh[t] - v;          // exclusive
  if (t == 255) *total_out = sh[255];       // rs[N] = E
}

__global__ __launch_bounds__(256) void scan3_kernel(const int* __restrict__ cnt, const int* __restrict__ boff,
                                                    int* __restrict__ off, int L){
  __shared__ int sh[256];
  int b = blockIdx.x, t = threadIdx.x;
  int base = b*2048 + t*8;
  int loc[8]; int s = 0;
  #pragma unroll
  for (int j = 0; j < 8; j++){ int i = base + j; int d = (i < L) ? cnt[i] : 0; loc[j] = d; s += d; }
  sh[t] = s; __syncthreads();
  for (int o = 1; o < 256; o <<= 1){
    int u = (t >= o) ? sh[t - o] : 0;
    __syncthreads();
    sh[t] += u;
    __syncthreads();
  }
  int excl = boff[b] + sh[t] - s;
  #pragma unroll
  for (int j = 0; j < 8; j++){ int i = base + j; if (i < L) off[i] = excl; excl += loc[j]; }
}

// P3: scatter packed (src<<8 | dst&255) into bucket-sorted order via LDS cursors
__global__ __launch_bounds__(256) void p3_scatter(const int* __restrict__ ei, int E, int NBLK,
    const int* __restrict__ off, int* __restrict__ tpack){
  __shared__ int cur[NBUCK];
  int b = blockIdx.x, t = threadIdx.x;
  cur[t]       = off[t*NBLK + b];
  cur[t + 256] = off[(t + 256)*NBLK + b];
  __syncthreads();
  int base = b*CHUNK;
  int lim = E - base; if (lim > CHUNK) lim = CHUNK;
  for (int i = t; i < lim; i += 256){
    int s = ei[base + i];
    int d = ei[E + base + i];
    int p = atomicAdd(&cur[d >> 8], 1);   // LDS atomic: global slot
    tpack[p] = (s << 8) | (d & 255);
  }
}

// P4: one block per bucket (256 consecutive dsts). Exact LDS histogram + scan
// -> rs slice (coalesced) + csr slice (bucket-local scatter).
__global__ __launch_bounds__(256) void p4_build(const int* __restrict__ tpack,
    const int* __restrict__ off, int NBLK, int E, int N,
    int* __restrict__ rs, int* __restrict__ csr){
  __shared__ int dc[256], sc[256];
  int q = blockIdx.x, t = threadIdx.x;
  int bstart = off[q*NBLK];
  int bend = (q == NBUCK-1) ? E : off[(q+1)*NBLK];
  dc[t] = 0;
  __syncthreads();
  for (int i = bstart + t; i < bend; i += 256)
    atomicAdd(&dc[tpack[i] & 255], 1);
  __syncthreads();
  int v = dc[t];
  sc[t] = v; __syncthreads();
  for (int o = 1; o < 256; o <<= 1){
    int u = (t >= o) ? sc[t - o] : 0;
    __syncthreads();
    sc[t] += u;
    __syncthreads();
  }
  int ex = sc[t] - v;                  // exclusive within bucket
  int gd = q*256 + t;
  if (gd < N) rs[gd] = bstart + ex;
  __syncthreads();
  dc[t] = ex;                          // reuse as cursor
  __syncthreads();
  for (int i = bstart + t; i < bend; i += 256){
    int p = tpack[i];
    int r = atomicAdd(&dc[p & 255], 1);
    csr[bstart + r] = p >> 8;
  }
}

// h[i] = x[i] + sum_{j in N(i)} x[j]
// One wave per node. 16 lanes per row (bf16x8 = 16B/lane), so each wave-load
// gathers 4 neighbor rows; unroll x2 = 8 rows in flight. fp32 accum; quad
// partials combined via shfl_xor(16,32); lanes 0-15 write the 256B row.
__global__ __launch_bounds__(256) void agg_kernel(const __bf16* __restrict__ xb,
    const int* __restrict__ rs, const int* __restrict__ csr,
    __bf16* __restrict__ hb, int N)
{
  int node = blockIdx.x*4 + (threadIdx.x >> 6);
  if (node >= N) return;
  int lane = threadIdx.x & 63;
  int quad = lane >> 4;
  int l16  = lane & 15;
  int s = rs[node], e = rs[node+1];
  float a[8] = {0.f,0.f,0.f,0.f,0.f,0.f,0.f,0.f};
  for (int base = s; base < e; base += 64){
    int idx = base + lane;
    int nb = (idx < e) ? csr[idx] : 0;
    int cnt = e - base; if (cnt > 64) cnt = 64;
    int t = 0;
    for (; t + 8 <= cnt; t += 8){
      int sA = __shfl(nb, t + quad);
      int sB = __shfl(nb, t + 4 + quad);
      bf16x8 vA = ((const bf16x8*)(xb + (long)sA*128))[l16];
      bf16x8 vB = ((const bf16x8*)(xb + (long)sB*128))[l16];
      #pragma unroll
      for (int j = 0; j < 8; j++) a[j] += (float)vA[j] + (float)vB[j];
    }
    for (; t < cnt; t += 4){
      int i = t + quad;
      int ic = (i < cnt) ? i : (cnt - 1);
      int sA = __shfl(nb, ic);
      bf16x8 vA = ((const bf16x8*)(xb + (long)sA*128))[l16];
      if (i < cnt){
        #pragma unroll
        for (int j = 0; j < 8; j++) a[j] += (float)vA[j];
      }
    }
  }
  if (quad == 0){
    bf16x8 sv = ((const bf16x8*)(xb + (long)node*128))[l16];
    #pragma unroll
    for (int j = 0; j < 8; j++) a[j] += (float)sv[j];
  }
  #pragma unroll
  for (int j = 0; j < 8; j++){
    a[j] += __shfl_xor(a[j], 16);
    a[j] += __shfl_xor(a[j], 32);
  }
  if (quad == 0){
    bf16x8 r;
    #pragma unroll
    for (int j = 0; j < 8; j++) r[j] = f2bf(a[j]);
    ((bf16x8*)(hb + (long)node*128))[l16] = r;
  }
}

// y_out[M,128] = ACT2( relu(A@W1 + b1) @ W2 + b2 + res )
// Fused MLP: hidden lives in LDS (padded row: 136 bf16 -> 2-way bank alias, free).
// 4 waves, each owns a 32-col stripe in BOTH gemms; one barrier total.
template<int ACT2>
__global__ __launch_bounds__(256) void fused_mlp(const __bf16* __restrict__ A,
    const __bf16* __restrict__ wf1, const __bf16* __restrict__ wf2,
    const float* __restrict__ b1, const float* __restrict__ b2,
    const __bf16* __restrict__ res, __bf16* __restrict__ out, int M)
{
  __shared__ __bf16 H[128][136];
  int lane = threadIdx.x & 63;
  int wid = threadIdx.x >> 6;
  long row0 = (long)blockIdx.x * 128;
  const bf16x8* w1v = (const bf16x8*)wf1;
  const bf16x8* w2v = (const bf16x8*)wf2;
  bf16x8 bv1[2][4], bv2[2][4];
  #pragma unroll
  for (int c2 = 0; c2 < 2; c2++)
    #pragma unroll
    for (int ks = 0; ks < 4; ks++){
      bv1[c2][ks] = w1v[((wid*2 + c2)*4 + ks)*64 + lane];
      bv2[c2][ks] = w2v[((wid*2 + c2)*4 + ks)*64 + lane];
    }
  int col0 = wid*32 + (lane & 15);
  float bb1_0 = b1[col0], bb1_1 = b1[col0 + 16];
  float bb2_0 = b2[col0], bb2_1 = b2[col0 + 16];
  int koff = (lane >> 4) << 3;
  // phase 1: H = relu(A@W1 + b1)
  #pragma unroll 2
  for (int rt = 0; rt < 8; rt++){
    long row = row0 + rt*16 + (lane & 15);
    long rowc = (row < M) ? row : (long)(M-1);
    const __bf16* ap = A + rowc*128 + koff;
    bf16x8 av[4];
    #pragma unroll
    for (int ks = 0; ks < 4; ks++)
      av[ks] = *(const bf16x8*)(ap + ks*32);
    f32x4 acc0 = {0.f,0.f,0.f,0.f}, acc1 = {0.f,0.f,0.f,0.f};
    #pragma unroll
    for (int ks = 0; ks < 4; ks++){
      acc0 = __builtin_amdgcn_mfma_f32_16x16x32_bf16(av[ks], bv1[0][ks], acc0, 0, 0, 0);
      acc1 = __builtin_amdgcn_mfma_f32_16x16x32_bf16(av[ks], bv1[1][ks], acc1, 0, 0, 0);
    }
    int r0 = rt*16 + ((lane >> 4) << 2);
    #pragma unroll
    for (int c2 = 0; c2 < 2; c2++){
      f32x4 acc = c2 ? acc1 : acc0;
      int col = col0 + c2*16;
      float bb = c2 ? bb1_1 : bb1_0;
      #pragma unroll
      for (int i = 0; i < 4; i++)
        H[r0 + i][col] = f2bf(fmaxf(acc[i] + bb, 0.f));
    }
  }
  __syncthreads();
  // phase 2: out = ACT2(H@W2 + b2 + res)
  #pragma unroll 2
  for (int rt = 0; rt < 8; rt++){
    int r = rt*16 + (lane & 15);
    bf16x8 av[4];
    #pragma unroll
    for (int ks = 0; ks < 4; ks++)
      av[ks] = *(const bf16x8*)(&H[r][ks*32 + koff]);
    f32x4 acc0 = {0.f,0.f,0.f,0.f}, acc1 = {0.f,0.f,0.f,0.f};
    #pragma unroll
    for (int ks = 0; ks < 4; ks++){
      acc0 = __builtin_amdgcn_mfma_f32_16x16x32_bf16(av[ks], bv2[0][ks], acc0, 0, 0, 0);
      acc1 = __builtin_amdgcn_mfma_f32_16x16x32_bf16(av[ks], bv2[1][ks], acc1, 0, 0, 0);
    }
    long orow0 = row0 + rt*16 + ((lane >> 4) << 2);
    #pragma unroll
    for (int c2 = 0; c2 < 2; c2++){
      f32x4 acc = c2 ? acc1 : acc0;
      int col = col0 + c2*16;
      float bb = c2 ? bb2_1 : bb2_0;
      #pragma unroll
      for (int i = 0; i < 4; i++){
        long orow = orow0 + i;
        if (orow < M){
          long idx = orow*128 + col;
          float v = acc[i] + bb + (float)res[idx];
          if (ACT2 == 2) v = (v > 0.f) ? v : (__expf(v) - 1.f);
          out[idx] = f2bf(v);
        }
      }
    }
  }
}

// out[M,128] = [y1|y2|y3] @ jkW + jkb   (K = 384, fp32 out, single pass)
__global__ __launch_bounds__(256) void jk_gemm(const __bf16* __restrict__ y1,
    const __bf16* __restrict__ y2, const __bf16* __restrict__ y3,
    const __bf16* __restrict__ wf, const float* __restrict__ bias,
    float* __restrict__ out, int M)
{
  int lane = threadIdx.x & 63;
  int wid = threadIdx.x >> 6;
  long row0 = (long)blockIdx.x * 128;
  const bf16x8* wfv = (const bf16x8*)wf;
  bf16x8 bv[2][12];
  #pragma unroll
  for (int c2 = 0; c2 < 2; c2++)
    #pragma unroll
    for (int ks = 0; ks < 12; ks++)
      bv[c2][ks] = wfv[(size_t)(6 + (ks>>2))*2048 + (size_t)((wid*2 + c2)*4 + (ks&3))*64 + lane];
  int col0 = wid*32 + (lane & 15);
  float b0 = bias[col0], b1 = bias[col0 + 16];
  int koff = (lane >> 4) << 3;
  const __bf16* ys[3] = {y1, y2, y3};
  #pragma unroll 1
  for (int rt = 0; rt < 8; rt++){
    long row = row0 + rt*16 + (lane & 15);
    long rowc = (row < M) ? row : (long)(M-1);
    f32x4 acc0 = {0.f,0.f,0.f,0.f}, acc1 = {0.f,0.f,0.f,0.f};
    #pragma unroll
    for (int ks = 0; ks < 12; ks++){
      bf16x8 av = *(const bf16x8*)(ys[ks>>2] + rowc*128 + (ks&3)*32 + koff);
      acc0 = __builtin_amdgcn_mfma_f32_16x16x32_bf16(av, bv[0][ks], acc0, 0, 0, 0);
      acc1 = __builtin_amdgcn_mfma_f32_16x16x32_bf16(av, bv[1][ks], acc1, 0, 0, 0);
    }
    long orow0 = row0 + rt*16 + ((lane >> 4) << 2);
    #pragma unroll
    for (int c2 = 0; c2 < 2; c2++){
      f32x4 acc = c2 ? acc1 : acc0;
      int col = col0 + c2*16;
      float bb = c2 ? b1 : b0;
      #pragma unroll
      for (int i = 0; i < 4; i++){
        long orow = orow0 + i;
        if (orow < M)
          out[orow*128 + col] = acc[i] + bb;
      }
    }
  }
}

extern "C" void kernel_launch(void* const* d_in, const int* in_sizes, int n_in,
                              void* d_out, int out_size, void* d_ws, size_t ws_size,
                              hipStream_t stream)
{
  const float* x   = (const float*)d_in[0];
  const int*   ei  = (const int*)d_in[1];
  const float* w1[3] = {(const float*)d_in[2], (const float*)d_in[6], (const float*)d_in[10]};
  const float* b1[3] = {(const float*)d_in[3], (const float*)d_in[7], (const float*)d_in[11]};
  const float* w2[3] = {(const float*)d_in[4], (const float*)d_in[8], (const float*)d_in[12]};
  const float* b2[3] = {(const float*)d_in[5], (const float*)d_in[9], (const float*)d_in[13]};
  const float* jkw = (const float*)d_in[14];
  const float* jkb = (const float*)d_in[15];
  int N = in_sizes[0] / 128;
  int E = in_sizes[1] / 2;
  float* outp = (float*)d_out;

  char* wptr = (char*)d_ws;
  auto alloc = [&](size_t bytes)->void*{
    void* p = (void*)wptr; wptr += (bytes + 255) & ~(size_t)255; return p;
  };
  int NBLK = (E + CHUNK - 1) / CHUNK;          // 391
  int L = NBUCK * NBLK;                        // 200K
  int* rs    = (int*)alloc((size_t)(N+1)*4);
  int* csr   = (int*)alloc((size_t)E*4);
  int* tpack = (int*)alloc((size_t)E*4);
  int* cnt   = (int*)alloc((size_t)L*4);
  int* off   = (int*)alloc((size_t)L*4);
  __bf16* y[4];
  for (int i = 0; i < 4; i++) y[i] = (__bf16*)alloc((size_t)N*128*2);
  __bf16* hb = (__bf16*)alloc((size_t)N*128*2);
  __bf16* wf = (__bf16*)alloc((size_t)9*16384*2);
  int nsb = (L + 2047) / 2048;                 // scan blocks (98)
  int* bsum = (int*)alloc((size_t)nsb*4);
  int* boff = (int*)alloc((size_t)nsb*4);

  WPack pk;
  pk.p[0] = w1[0]; pk.p[1] = w2[0];
  pk.p[2] = w1[1]; pk.p[3] = w2[1];
  pk.p[4] = w1[2]; pk.p[5] = w2[2];
  pk.p[6] = jkw; pk.p[7] = jkw + 16384; pk.p[8] = jkw + 32768;
  conv_w_kernel<<<576, 256, 0, stream>>>(pk, wf);

  f2b_kernel<<<(N*128/8 + 255)/256, 256, 0, stream>>>(x, y[0], N*128/8);

  p1_count<<<NBLK, 256, 0, stream>>>(ei, E, NBLK, cnt);
  scan1_kernel<<<nsb, 256, 0, stream>>>(cnt, bsum, L);
  scan2_kernel<<<1, 256, 0, stream>>>(bsum, boff, nsb, rs + N);   // rs[N] = E
  scan3_kernel<<<nsb, 256, 0, stream>>>(cnt, boff, off, L);
  p3_scatter<<<NBLK, 256, 0, stream>>>(ei, E, NBLK, off, tpack);
  p4_build<<<NBUCK, 256, 0, stream>>>(tpack, off, NBLK, E, N, rs, csr);

  int gemm_blocks = (N + 127)/128;
  for (int l = 0; l < 3; l++){
    agg_kernel<<<(N + 3)/4, 256, 0, stream>>>(y[l], rs, csr, hb, N);
    if (l < 2)
      fused_mlp<2><<<gemm_blocks, 256, 0, stream>>>(hb, wf + (size_t)(2*l)*16384, wf + (size_t)(2*l+1)*16384,
                                                    b1[l], b2[l], y[l], y[l+1], N);
    else
      fused_mlp<0><<<gemm_blocks, 256, 0, stream>>>(hb, wf + (size_t)(2*l)*16384, wf + (size_t)(2*l+1)*16384,
                                                    b1[l], b2[l], y[l], y[l+1], N);
  }
  jk_gemm<<<gemm_blocks, 256, 0, stream>>>(y[1], y[2], y[3], wf, jkb, outp, N);
}

// Round 8
// 404.031 us; speedup vs baseline: 2.7201x; 1.0608x over previous
//
#include <hip/hip_runtime.h>

typedef __bf16 bf16x8 __attribute__((ext_vector_type(8)));
typedef float f32x4 __attribute__((ext_vector_type(4)));

#define CHUNK 4096
#define NBUCK 512

struct WPack { const float* p[9]; };

__device__ inline __bf16 f2bf(float f){ return (__bf16)f; }

// Combined prep: blocks [0,576) convert 9 fp32 128x128 weight mats into MFMA
// B-fragment layout (bf16); blocks [576,...) bulk-convert x fp32->bf16.
// wf element index: m*16384 + c*2048 + ks*512 + lane*8 + j
//   holds W[k][col], k = ks*32 + (lane>>4)*8 + j, col = c*16 + (lane&15)
__global__ __launch_bounds__(256) void prep_kernel(WPack pk, __bf16* __restrict__ wf,
    const float* __restrict__ x, __bf16* __restrict__ xb, int n8){
  int b = blockIdx.x, t = threadIdx.x;
  if (b < 576){
    int tid = b*256 + t;
    int m = tid >> 14;
    int r = tid & 16383;
    int j = r & 7;
    int lane = (r >> 3) & 63;
    int ks = (r >> 9) & 3;
    int c = r >> 11;
    int k = ks*32 + ((lane>>4)<<3) + j;
    int col = (c<<4) + (lane & 15);
    wf[tid] = f2bf(pk.p[m][k*128 + col]);
  } else {
    int i = (b - 576)*256 + t;
    if (i >= n8) return;
    f32x4 a = ((const f32x4*)x)[2*i];
    f32x4 bb = ((const f32x4*)x)[2*i+1];
    bf16x8 r;
    r[0]=f2bf(a[0]); r[1]=f2bf(a[1]); r[2]=f2bf(a[2]); r[3]=f2bf(a[3]);
    r[4]=f2bf(bb[0]); r[5]=f2bf(bb[1]); r[6]=f2bf(bb[2]); r[7]=f2bf(bb[3]);
    ((bf16x8*)xb)[i] = r;
  }
}

// ---- CSR build via two-level bucket sort (no global atomics) ----
// P1: per-block LDS histogram over 512 buckets (dst>>8); cnt[q*NBLK + b]
__global__ __launch_bounds__(256) void p1_count(const int* __restrict__ ei, int E, int NBLK,
    int* __restrict__ cnt){
  __shared__ int h[NBUCK];
  int b = blockIdx.x, t = threadIdx.x;
  h[t] = 0; h[t + 256] = 0;
  __syncthreads();
  int base = b*CHUNK;
  int lim = E - base; if (lim > CHUNK) lim = CHUNK;
  for (int i = t; i < lim; i += 256)
    atomicAdd(&h[ei[E + base + i] >> 8], 1);     // dst row
  __syncthreads();
  cnt[t*NBLK + b] = h[t];
  cnt[(t + 256)*NBLK + b] = h[t + 256];
}

// ---- 3-phase parallel exclusive scan of cnt[L] -> off[L] (+ total) ----
__global__ __launch_bounds__(256) void scan1_kernel(const int* __restrict__ cnt, int* __restrict__ bsum, int L){
  __shared__ int sh[256];
  int b = blockIdx.x, t = threadIdx.x;
  int base = b*2048 + t*8;
  int s = 0;
  #pragma unroll
  for (int j = 0; j < 8; j++){ int i = base + j; if (i < L) s += cnt[i]; }
  sh[t] = s; __syncthreads();
  for (int off = 128; off > 0; off >>= 1){
    if (t < off) sh[t] += sh[t + off];
    __syncthreads();
  }
  if (t == 0) bsum[b] = sh[0];
}

__global__ __launch_bounds__(256) void scan2_kernel(const int* __restrict__ bsum, int* __restrict__ boff,
                                                    int NB, int* __restrict__ total_out){
  __shared__ int sh[256];
  int t = threadIdx.x;
  int v = (t < NB) ? bsum[t] : 0;
  sh[t] = v; __syncthreads();
  for (int off = 1; off < 256; off <<= 1){
    int u = (t >= off) ? sh[t - off] : 0;
    __syncthreads();
    sh[t] += u;
    __syncthreads();
  }
  if (t < NB) boff[t] = sh[t] - v;          // exclusive
  if (t == 255) *total_out = sh[255];       // rs[N] = E
}

__global__ __launch_bounds__(256) void scan3_kernel(const int* __restrict__ cnt, const int* __restrict__ boff,
                                                    int* __restrict__ off, int L){
  __shared__ int sh[256];
  int b = blockIdx.x, t = threadIdx.x;
  int base = b*2048 + t*8;
  int loc[8]; int s = 0;
  #pragma unroll
  for (int j = 0; j < 8; j++){ int i = base + j; int d = (i < L) ? cnt[i] : 0; loc[j] = d; s += d; }
  sh[t] = s; __syncthreads();
  for (int o = 1; o < 256; o <<= 1){
    int u = (t >= o) ? sh[t - o] : 0;
    __syncthreads();
    sh[t] += u;
    __syncthreads();
  }
  int excl = boff[b] + sh[t] - s;
  #pragma unroll
  for (int j = 0; j < 8; j++){ int i = base + j; if (i < L) off[i] = excl; excl += loc[j]; }
}

// P3: scatter packed (src<<8 | dst&255) into bucket-sorted order via LDS cursors
__global__ __launch_bounds__(256) void p3_scatter(const int* __restrict__ ei, int E, int NBLK,
    const int* __restrict__ off, int* __restrict__ tpack){
  __shared__ int cur[NBUCK];
  int b = blockIdx.x, t = threadIdx.x;
  cur[t]       = off[t*NBLK + b];
  cur[t + 256] = off[(t + 256)*NBLK + b];
  __syncthreads();
  int base = b*CHUNK;
  int lim = E - base; if (lim > CHUNK) lim = CHUNK;
  for (int i = t; i < lim; i += 256){
    int s = ei[base + i];
    int d = ei[E + base + i];
    int p = atomicAdd(&cur[d >> 8], 1);   // LDS atomic: global slot
    tpack[p] = (s << 8) | (d & 255);
  }
}

// P4: one block per bucket (256 consecutive dsts). Exact LDS histogram + scan
// -> rs slice (coalesced) + csr slice (bucket-local scatter).
__global__ __launch_bounds__(256) void p4_build(const int* __restrict__ tpack,
    const int* __restrict__ off, int NBLK, int E, int N,
    int* __restrict__ rs, int* __restrict__ csr){
  __shared__ int dc[256], sc[256];
  int q = blockIdx.x, t = threadIdx.x;
  int bstart = off[q*NBLK];
  int bend = (q == NBUCK-1) ? E : off[(q+1)*NBLK];
  dc[t] = 0;
  __syncthreads();
  for (int i = bstart + t; i < bend; i += 256)
    atomicAdd(&dc[tpack[i] & 255], 1);
  __syncthreads();
  int v = dc[t];
  sc[t] = v; __syncthreads();
  for (int o = 1; o < 256; o <<= 1){
    int u = (t >= o) ? sc[t - o] : 0;
    __syncthreads();
    sc[t] += u;
    __syncthreads();
  }
  int ex = sc[t] - v;                  // exclusive within bucket
  int gd = q*256 + t;
  if (gd < N) rs[gd] = bstart + ex;
  __syncthreads();
  dc[t] = ex;                          // reuse as cursor
  __syncthreads();
  for (int i = bstart + t; i < bend; i += 256){
    int p = tpack[i];
    int r = atomicAdd(&dc[p & 255], 1);
    csr[bstart + r] = p >> 8;
  }
}

// h[i] = x[i] + sum_{j in N(i)} x[j]
// One wave per node. 16 lanes per row (bf16x8 = 16B/lane), so each wave-load
// gathers 4 neighbor rows; unroll(2) -> up to 16 rows in flight. fp32 accum;
// quad partials combined via shfl_xor(16,32); lanes 0-15 write the 256B row.
__global__ __launch_bounds__(256) void agg_kernel(const __bf16* __restrict__ xb,
    const int* __restrict__ rs, const int* __restrict__ csr,
    __bf16* __restrict__ hb, int N)
{
  int node = blockIdx.x*4 + (threadIdx.x >> 6);
  if (node >= N) return;
  int lane = threadIdx.x & 63;
  int quad = lane >> 4;
  int l16  = lane & 15;
  int s = rs[node], e = rs[node+1];
  float a[8] = {0.f,0.f,0.f,0.f,0.f,0.f,0.f,0.f};
  for (int base = s; base < e; base += 64){
    int idx = base + lane;
    int nb = (idx < e) ? csr[idx] : 0;
    int cnt = e - base; if (cnt > 64) cnt = 64;
    int t = 0;
    #pragma unroll 2
    for (; t + 8 <= cnt; t += 8){
      int sA = __shfl(nb, t + quad);
      int sB = __shfl(nb, t + 4 + quad);
      bf16x8 vA = ((const bf16x8*)(xb + (long)sA*128))[l16];
      bf16x8 vB = ((const bf16x8*)(xb + (long)sB*128))[l16];
      #pragma unroll
      for (int j = 0; j < 8; j++) a[j] += (float)vA[j] + (float)vB[j];
    }
    for (; t < cnt; t += 4){
      int i = t + quad;
      int ic = (i < cnt) ? i : (cnt - 1);
      int sA = __shfl(nb, ic);
      bf16x8 vA = ((const bf16x8*)(xb + (long)sA*128))[l16];
      if (i < cnt){
        #pragma unroll
        for (int j = 0; j < 8; j++) a[j] += (float)vA[j];
      }
    }
  }
  if (quad == 0){
    bf16x8 sv = ((const bf16x8*)(xb + (long)node*128))[l16];
    #pragma unroll
    for (int j = 0; j < 8; j++) a[j] += (float)sv[j];
  }
  #pragma unroll
  for (int j = 0; j < 8; j++){
    a[j] += __shfl_xor(a[j], 16);
    a[j] += __shfl_xor(a[j], 32);
  }
  if (quad == 0){
    bf16x8 r;
    #pragma unroll
    for (int j = 0; j < 8; j++) r[j] = f2bf(a[j]);
    ((bf16x8*)(hb + (long)node*128))[l16] = r;
  }
}

// y_out[M,128] = ACT2( relu(A@W1 + b1) @ W2 + b2 + res )
// Fused MLP: hidden lives in LDS (padded row: 136 bf16 -> 2-way bank alias, free).
// 4 waves, each owns a 32-col stripe in BOTH gemms; one barrier total.
template<int ACT2>
__global__ __launch_bounds__(256) void fused_mlp(const __bf16* __restrict__ A,
    const __bf16* __restrict__ wf1, const __bf16* __restrict__ wf2,
    const float* __restrict__ b1, const float* __restrict__ b2,
    const __bf16* __restrict__ res, __bf16* __restrict__ out, int M)
{
  __shared__ __bf16 H[128][136];
  int lane = threadIdx.x & 63;
  int wid = threadIdx.x >> 6;
  long row0 = (long)blockIdx.x * 128;
  const bf16x8* w1v = (const bf16x8*)wf1;
  const bf16x8* w2v = (const bf16x8*)wf2;
  bf16x8 bv1[2][4], bv2[2][4];
  #pragma unroll
  for (int c2 = 0; c2 < 2; c2++)
    #pragma unroll
    for (int ks = 0; ks < 4; ks++){
      bv1[c2][ks] = w1v[((wid*2 + c2)*4 + ks)*64 + lane];
      bv2[c2][ks] = w2v[((wid*2 + c2)*4 + ks)*64 + lane];
    }
  int col0 = wid*32 + (lane & 15);
  float bb1_0 = b1[col0], bb1_1 = b1[col0 + 16];
  float bb2_0 = b2[col0], bb2_1 = b2[col0 + 16];
  int koff = (lane >> 4) << 3;
  // phase 1: H = relu(A@W1 + b1)
  #pragma unroll 2
  for (int rt = 0; rt < 8; rt++){
    long row = row0 + rt*16 + (lane & 15);
    long rowc = (row < M) ? row : (long)(M-1);
    const __bf16* ap = A + rowc*128 + koff;
    bf16x8 av[4];
    #pragma unroll
    for (int ks = 0; ks < 4; ks++)
      av[ks] = *(const bf16x8*)(ap + ks*32);
    f32x4 acc0 = {0.f,0.f,0.f,0.f}, acc1 = {0.f,0.f,0.f,0.f};
    #pragma unroll
    for (int ks = 0; ks < 4; ks++){
      acc0 = __builtin_amdgcn_mfma_f32_16x16x32_bf16(av[ks], bv1[0][ks], acc0, 0, 0, 0);
      acc1 = __builtin_amdgcn_mfma_f32_16x16x32_bf16(av[ks], bv1[1][ks], acc1, 0, 0, 0);
    }
    int r0 = rt*16 + ((lane >> 4) << 2);
    #pragma unroll
    for (int c2 = 0; c2 < 2; c2++){
      f32x4 acc = c2 ? acc1 : acc0;
      int col = col0 + c2*16;
      float bb = c2 ? bb1_1 : bb1_0;
      #pragma unroll
      for (int i = 0; i < 4; i++)
        H[r0 + i][col] = f2bf(fmaxf(acc[i] + bb, 0.f));
    }
  }
  __syncthreads();
  // phase 2: out = ACT2(H@W2 + b2 + res)
  #pragma unroll 2
  for (int rt = 0; rt < 8; rt++){
    int r = rt*16 + (lane & 15);
    bf16x8 av[4];
    #pragma unroll
    for (int ks = 0; ks < 4; ks++)
      av[ks] = *(const bf16x8*)(&H[r][ks*32 + koff]);
    f32x4 acc0 = {0.f,0.f,0.f,0.f}, acc1 = {0.f,0.f,0.f,0.f};
    #pragma unroll
    for (int ks = 0; ks < 4; ks++){
      acc0 = __builtin_amdgcn_mfma_f32_16x16x32_bf16(av[ks], bv2[0][ks], acc0, 0, 0, 0);
      acc1 = __builtin_amdgcn_mfma_f32_16x16x32_bf16(av[ks], bv2[1][ks], acc1, 0, 0, 0);
    }
    long orow0 = row0 + rt*16 + ((lane >> 4) << 2);
    #pragma unroll
    for (int c2 = 0; c2 < 2; c2++){
      f32x4 acc = c2 ? acc1 : acc0;
      int col = col0 + c2*16;
      float bb = c2 ? bb2_1 : bb2_0;
      #pragma unroll
      for (int i = 0; i < 4; i++){
        long orow = orow0 + i;
        if (orow < M){
          long idx = orow*128 + col;
          float v = acc[i] + bb + (float)res[idx];
          if (ACT2 == 2) v = (v > 0.f) ? v : (__expf(v) - 1.f);
          out[idx] = f2bf(v);
        }
      }
    }
  }
}

// Layer-3 MLP fused with JK projection. y3 = relu(A@W1+b1)@W2 + b2 + y2 stays
// entirely in LDS; phase 3 computes out = [y1|y2|y3] @ jkW + jkb (fp32 out).
__global__ __launch_bounds__(256) void fused_mlp_jk(const __bf16* __restrict__ A,
    const __bf16* __restrict__ y1g, const __bf16* __restrict__ y2g,
    const __bf16* __restrict__ wf1, const __bf16* __restrict__ wf2,
    const __bf16* __restrict__ wfjk,
    const float* __restrict__ b1, const float* __restrict__ b2,
    const float* __restrict__ jkb, float* __restrict__ out, int M)
{
  __shared__ __bf16 H[128][136];
  __shared__ __bf16 Y3[128][136];
  int lane = threadIdx.x & 63;
  int wid = threadIdx.x >> 6;
  long row0 = (long)blockIdx.x * 128;
  const bf16x8* w1v = (const bf16x8*)wf1;
  const bf16x8* w2v = (const bf16x8*)wf2;
  bf16x8 bv1[2][4], bv2[2][4];
  #pragma unroll
  for (int c2 = 0; c2 < 2; c2++)
    #pragma unroll
    for (int ks = 0; ks < 4; ks++){
      bv1[c2][ks] = w1v[((wid*2 + c2)*4 + ks)*64 + lane];
      bv2[c2][ks] = w2v[((wid*2 + c2)*4 + ks)*64 + lane];
    }
  int col0 = wid*32 + (lane & 15);
  float bb1_0 = b1[col0], bb1_1 = b1[col0 + 16];
  float bb2_0 = b2[col0], bb2_1 = b2[col0 + 16];
  int koff = (lane >> 4) << 3;
  // phase 1: H = relu(A@W1 + b1)
  #pragma unroll 2
  for (int rt = 0; rt < 8; rt++){
    long row = row0 + rt*16 + (lane & 15);
    long rowc = (row < M) ? row : (long)(M-1);
    const __bf16* ap = A + rowc*128 + koff;
    bf16x8 av[4];
    #pragma unroll
    for (int ks = 0; ks < 4; ks++)
      av[ks] = *(const bf16x8*)(ap + ks*32);
    f32x4 acc0 = {0.f,0.f,0.f,0.f}, acc1 = {0.f,0.f,0.f,0.f};
    #pragma unroll
    for (int ks = 0; ks < 4; ks++){
      acc0 = __builtin_amdgcn_mfma_f32_16x16x32_bf16(av[ks], bv1[0][ks], acc0, 0, 0, 0);
      acc1 = __builtin_amdgcn_mfma_f32_16x16x32_bf16(av[ks], bv1[1][ks], acc1, 0, 0, 0);
    }
    int r0 = rt*16 + ((lane >> 4) << 2);
    #pragma unroll
    for (int c2 = 0; c2 < 2; c2++){
      f32x4 acc = c2 ? acc1 : acc0;
      int col = col0 + c2*16;
      float bb = c2 ? bb1_1 : bb1_0;
      #pragma unroll
      for (int i = 0; i < 4; i++)
        H[r0 + i][col] = f2bf(fmaxf(acc[i] + bb, 0.f));
    }
  }
  __syncthreads();
  // phase 2: Y3 = H@W2 + b2 + y2 (no activation, layer 3)
  #pragma unroll 2
  for (int rt = 0; rt < 8; rt++){
    int r = rt*16 + (lane & 15);
    bf16x8 av[4];
    #pragma unroll
    for (int ks = 0; ks < 4; ks++)
      av[ks] = *(const bf16x8*)(&H[r][ks*32 + koff]);
    f32x4 acc0 = {0.f,0.f,0.f,0.f}, acc1 = {0.f,0.f,0.f,0.f};
    #pragma unroll
    for (int ks = 0; ks < 4; ks++){
      acc0 = __builtin_amdgcn_mfma_f32_16x16x32_bf16(av[ks], bv2[0][ks], acc0, 0, 0, 0);
      acc1 = __builtin_amdgcn_mfma_f32_16x16x32_bf16(av[ks], bv2[1][ks], acc1, 0, 0, 0);
    }
    long orow0 = row0 + rt*16 + ((lane >> 4) << 2);
    int r0 = rt*16 + ((lane >> 4) << 2);
    #pragma unroll
    for (int c2 = 0; c2 < 2; c2++){
      f32x4 acc = c2 ? acc1 : acc0;
      int col = col0 + c2*16;
      float bb = c2 ? bb2_1 : bb2_0;
      #pragma unroll
      for (int i = 0; i < 4; i++){
        long orow = orow0 + i;
        float rv = (orow < M) ? (float)y2g[orow*128 + col] : 0.f;
        Y3[r0 + i][col] = f2bf(acc[i] + bb + rv);
      }
    }
  }
  __syncthreads();
  // phase 3: out = [y1|y2|Y3] @ jkW + jkb  (K = 384, fp32 out)
  const bf16x8* wjv = (const bf16x8*)wfjk;
  bf16x8 bvj[2][12];
  #pragma unroll
  for (int c2 = 0; c2 < 2; c2++)
    #pragma unroll
    for (int ks = 0; ks < 12; ks++)
      bvj[c2][ks] = wjv[(size_t)(ks>>2)*2048 + (size_t)((wid*2 + c2)*4 + (ks&3))*64 + lane];
  float jb0 = jkb[col0], jb1 = jkb[col0 + 16];
  #pragma unroll 1
  for (int rt = 0; rt < 8; rt++){
    long row = row0 + rt*16 + (lane & 15);
    long rowc = (row < M) ? row : (long)(M-1);
    int rl = rt*16 + (lane & 15);
    f32x4 acc0 = {0.f,0.f,0.f,0.f}, acc1 = {0.f,0.f,0.f,0.f};
    #pragma unroll
    for (int ks = 0; ks < 12; ks++){
      bf16x8 av;
      if (ks < 4)      av = *(const bf16x8*)(y1g + rowc*128 + ks*32 + koff);
      else if (ks < 8) av = *(const bf16x8*)(y2g + rowc*128 + (ks-4)*32 + koff);
      else             av = *(const bf16x8*)(&Y3[rl][(ks-8)*32 + koff]);
      acc0 = __builtin_amdgcn_mfma_f32_16x16x32_bf16(av, bvj[0][ks], acc0, 0, 0, 0);
      acc1 = __builtin_amdgcn_mfma_f32_16x16x32_bf16(av, bvj[1][ks], acc1, 0, 0, 0);
    }
    long orow0 = row0 + rt*16 + ((lane >> 4) << 2);
    #pragma unroll
    for (int c2 = 0; c2 < 2; c2++){
      f32x4 acc = c2 ? acc1 : acc0;
      int col = col0 + c2*16;
      float bb = c2 ? jb1 : jb0;
      #pragma unroll
      for (int i = 0; i < 4; i++){
        long orow = orow0 + i;
        if (orow < M)
          out[orow*128 + col] = acc[i] + bb;
      }
    }
  }
}

extern "C" void kernel_launch(void* const* d_in, const int* in_sizes, int n_in,
                              void* d_out, int out_size, void* d_ws, size_t ws_size,
                              hipStream_t stream)
{
  const float* x   = (const float*)d_in[0];
  const int*   ei  = (const int*)d_in[1];
  const float* w1[3] = {(const float*)d_in[2], (const float*)d_in[6], (const float*)d_in[10]};
  const float* b1[3] = {(const float*)d_in[3], (const float*)d_in[7], (const float*)d_in[11]};
  const float* w2[3] = {(const float*)d_in[4], (const float*)d_in[8], (const float*)d_in[12]};
  const float* b2[3] = {(const float*)d_in[5], (const float*)d_in[9], (const float*)d_in[13]};
  const float* jkw = (const float*)d_in[14];
  const float* jkb = (const float*)d_in[15];
  int N = in_sizes[0] / 128;
  int E = in_sizes[1] / 2;
  float* outp = (float*)d_out;

  char* wptr = (char*)d_ws;
  auto alloc = [&](size_t bytes)->void*{
    void* p = (void*)wptr; wptr += (bytes + 255) & ~(size_t)255; return p;
  };
  int NBLK = (E + CHUNK - 1) / CHUNK;          // 391
  int L = NBUCK * NBLK;                        // 200K
  int* rs    = (int*)alloc((size_t)(N+1)*4);
  int* csr   = (int*)alloc((size_t)E*4);
  int* tpack = (int*)alloc((size_t)E*4);
  int* cnt   = (int*)alloc((size_t)L*4);
  int* off   = (int*)alloc((size_t)L*4);
  __bf16* y[3];
  for (int i = 0; i < 3; i++) y[i] = (__bf16*)alloc((size_t)N*128*2);
  __bf16* hb = (__bf16*)alloc((size_t)N*128*2);
  __bf16* wf = (__bf16*)alloc((size_t)9*16384*2);
  int nsb = (L + 2047) / 2048;                 // scan blocks (98)
  int* bsum = (int*)alloc((size_t)nsb*4);
  int* boff = (int*)alloc((size_t)nsb*4);

  WPack pk;
  pk.p[0] = w1[0]; pk.p[1] = w2[0];
  pk.p[2] = w1[1]; pk.p[3] = w2[1];
  pk.p[4] = w1[2]; pk.p[5] = w2[2];
  pk.p[6] = jkw; pk.p[7] = jkw + 16384; pk.p[8] = jkw + 32768;
  int n8 = N*128/8;
  prep_kernel<<<576 + (n8 + 255)/256, 256, 0, stream>>>(pk, wf, x, y[0], n8);

  p1_count<<<NBLK, 256, 0, stream>>>(ei, E, NBLK, cnt);
  scan1_kernel<<<nsb, 256, 0, stream>>>(cnt, bsum, L);
  scan2_kernel<<<1, 256, 0, stream>>>(bsum, boff, nsb, rs + N);   // rs[N] = E
  scan3_kernel<<<nsb, 256, 0, stream>>>(cnt, boff, off, L);
  p3_scatter<<<NBLK, 256, 0, stream>>>(ei, E, NBLK, off, tpack);
  p4_build<<<NBUCK, 256, 0, stream>>>(tpack, off, NBLK, E, N, rs, csr);

  int gemm_blocks = (N + 127)/128;
  for (int l = 0; l < 3; l++){
    agg_kernel<<<(N + 3)/4, 256, 0, stream>>>(y[l], rs, csr, hb, N);
    if (l < 2)
      fused_mlp<2><<<gemm_blocks, 256, 0, stream>>>(hb, wf + (size_t)(2*l)*16384, wf + (size_t)(2*l+1)*16384,
                                                    b1[l], b2[l], y[l], y[l+1], N);
    else
      fused_mlp_jk<<<gemm_blocks, 256, 0, stream>>>(hb, y[1], y[2],
                                                    wf + (size_t)4*16384, wf + (size_t)5*16384, wf + (size_t)6*16384,
                                                    b1[2], b2[2], jkb, outp, N);
  }
}

// Round 9
// 391.924 us; speedup vs baseline: 2.8041x; 1.0309x over previous
//
#include <hip/hip_runtime.h>

typedef __bf16 bf16x8 __attribute__((ext_vector_type(8)));
typedef float f32x4 __attribute__((ext_vector_type(4)));

#define CHUNK 4096
#define NBUCK 512

struct WPack { const float* p[9]; };

__device__ inline __bf16 f2bf(float f){ return (__bf16)f; }

// Swizzled 128x128 bf16 LDS tile (32KB, no pad). Element (r,c) lives at
// r*128 + (((c>>3) ^ (r&7))<<3) + (c&7)  -> byte swizzle ((r&7)<<4), the
// verified fix for stride-256B ds_read_b128 column patterns.
__device__ inline int hswz(int r, int c){
  return (r << 7) + ((((c >> 3) ^ (r & 7)) << 3) | (c & 7));
}
__device__ inline const __bf16* hvec(const __bf16* H, int r, int g){  // g = 8-elem granule 0..15
  return H + (r << 7) + (((g ^ (r & 7)) & 15) << 3);
}

// Combined prep: blocks [0,576) convert 9 fp32 128x128 weight mats into MFMA
// B-fragment layout (bf16); blocks [576,...) bulk-convert x fp32->bf16.
// wf element index: m*16384 + c*2048 + ks*512 + lane*8 + j
//   holds W[k][col], k = ks*32 + (lane>>4)*8 + j, col = c*16 + (lane&15)
__global__ __launch_bounds__(256) void prep_kernel(WPack pk, __bf16* __restrict__ wf,
    const float* __restrict__ x, __bf16* __restrict__ xb, int n8){
  int b = blockIdx.x, t = threadIdx.x;
  if (b < 576){
    int tid = b*256 + t;
    int m = tid >> 14;
    int r = tid & 16383;
    int j = r & 7;
    int lane = (r >> 3) & 63;
    int ks = (r >> 9) & 3;
    int c = r >> 11;
    int k = ks*32 + ((lane>>4)<<3) + j;
    int col = (c<<4) + (lane & 15);
    wf[tid] = f2bf(pk.p[m][k*128 + col]);
  } else {
    int i = (b - 576)*256 + t;
    if (i >= n8) return;
    f32x4 a = ((const f32x4*)x)[2*i];
    f32x4 bb = ((const f32x4*)x)[2*i+1];
    bf16x8 r;
    r[0]=f2bf(a[0]); r[1]=f2bf(a[1]); r[2]=f2bf(a[2]); r[3]=f2bf(a[3]);
    r[4]=f2bf(bb[0]); r[5]=f2bf(bb[1]); r[6]=f2bf(bb[2]); r[7]=f2bf(bb[3]);
    ((bf16x8*)xb)[i] = r;
  }
}

// ---- CSR build via two-level bucket sort (no global atomics) ----
__global__ __launch_bounds__(256) void p1_count(const int* __restrict__ ei, int E, int NBLK,
    int* __restrict__ cnt){
  __shared__ int h[NBUCK];
  int b = blockIdx.x, t = threadIdx.x;
  h[t] = 0; h[t + 256] = 0;
  __syncthreads();
  int base = b*CHUNK;
  int lim = E - base; if (lim > CHUNK) lim = CHUNK;
  for (int i = t; i < lim; i += 256)
    atomicAdd(&h[ei[E + base + i] >> 8], 1);     // dst row
  __syncthreads();
  cnt[t*NBLK + b] = h[t];
  cnt[(t + 256)*NBLK + b] = h[t + 256];
}

__global__ __launch_bounds__(256) void scan1_kernel(const int* __restrict__ cnt, int* __restrict__ bsum, int L){
  __shared__ int sh[256];
  int b = blockIdx.x, t = threadIdx.x;
  int base = b*2048 + t*8;
  int s = 0;
  #pragma unroll
  for (int j = 0; j < 8; j++){ int i = base + j; if (i < L) s += cnt[i]; }
  sh[t] = s; __syncthreads();
  for (int off = 128; off > 0; off >>= 1){
    if (t < off) sh[t] += sh[t + off];
    __syncthreads();
  }
  if (t == 0) bsum[b] = sh[0];
}

__global__ __launch_bounds__(256) void scan2_kernel(const int* __restrict__ bsum, int* __restrict__ boff,
                                                    int NB, int* __restrict__ total_out){
  __shared__ int sh[256];
  int t = threadIdx.x;
  int v = (t < NB) ? bsum[t] : 0;
  sh[t] = v; __syncthreads();
  for (int off = 1; off < 256; off <<= 1){
    int u = (t >= off) ? sh[t - off] : 0;
    __syncthreads();
    sh[t] += u;
    __syncthreads();
  }
  if (t < NB) boff[t] = sh[t] - v;          // exclusive
  if (t == 255) *total_out = sh[255];       // rs[N] = E
}

__global__ __launch_bounds__(256) void scan3_kernel(const int* __restrict__ cnt, const int* __restrict__ boff,
                                                    int* __restrict__ off, int L){
  __shared__ int sh[256];
  int b = blockIdx.x, t = threadIdx.x;
  int base = b*2048 + t*8;
  int loc[8]; int s = 0;
  #pragma unroll
  for (int j = 0; j < 8; j++){ int i = base + j; int d = (i < L) ? cnt[i] : 0; loc[j] = d; s += d; }
  sh[t] = s; __syncthreads();
  for (int o = 1; o < 256; o <<= 1){
    int u = (t >= o) ? sh[t - o] : 0;
    __syncthreads();
    sh[t] += u;
    __syncthreads();
  }
  int excl = boff[b] + sh[t] - s;
  #pragma unroll
  for (int j = 0; j < 8; j++){ int i = base + j; if (i < L) off[i] = excl; excl += loc[j]; }
}

__global__ __launch_bounds__(256) void p3_scatter(const int* __restrict__ ei, int E, int NBLK,
    const int* __restrict__ off, int* __restrict__ tpack){
  __shared__ int cur[NBUCK];
  int b = blockIdx.x, t = threadIdx.x;
  cur[t]       = off[t*NBLK + b];
  cur[t + 256] = off[(t + 256)*NBLK + b];
  __syncthreads();
  int base = b*CHUNK;
  int lim = E - base; if (lim > CHUNK) lim = CHUNK;
  for (int i = t; i < lim; i += 256){
    int s = ei[base + i];
    int d = ei[E + base + i];
    int p = atomicAdd(&cur[d >> 8], 1);   // LDS atomic: global slot
    tpack[p] = (s << 8) | (d & 255);
  }
}

__global__ __launch_bounds__(256) void p4_build(const int* __restrict__ tpack,
    const int* __restrict__ off, int NBLK, int E, int N,
    int* __restrict__ rs, int* __restrict__ csr){
  __shared__ int dc[256], sc[256];
  int q = blockIdx.x, t = threadIdx.x;
  int bstart = off[q*NBLK];
  int bend = (q == NBUCK-1) ? E : off[(q+1)*NBLK];
  dc[t] = 0;
  __syncthreads();
  for (int i = bstart + t; i < bend; i += 256)
    atomicAdd(&dc[tpack[i] & 255], 1);
  __syncthreads();
  int v = dc[t];
  sc[t] = v; __syncthreads();
  for (int o = 1; o < 256; o <<= 1){
    int u = (t >= o) ? sc[t - o] : 0;
    __syncthreads();
    sc[t] += u;
    __syncthreads();
  }
  int ex = sc[t] - v;                  // exclusive within bucket
  int gd = q*256 + t;
  if (gd < N) rs[gd] = bstart + ex;
  __syncthreads();
  dc[t] = ex;                          // reuse as cursor
  __syncthreads();
  for (int i = bstart + t; i < bend; i += 256){
    int p = tpack[i];
    int r = atomicAdd(&dc[p & 255], 1);
    csr[bstart + r] = p >> 8;
  }
}

// h[i] = x[i] + sum_{j in N(i)} x[j]   (unchanged; at fabric byte floor)
__global__ __launch_bounds__(256) void agg_kernel(const __bf16* __restrict__ xb,
    const int* __restrict__ rs, const int* __restrict__ csr,
    __bf16* __restrict__ hb, int N)
{
  int node = blockIdx.x*4 + (threadIdx.x >> 6);
  if (node >= N) return;
  int lane = threadIdx.x & 63;
  int quad = lane >> 4;
  int l16  = lane & 15;
  int s = rs[node], e = rs[node+1];
  float a[8] = {0.f,0.f,0.f,0.f,0.f,0.f,0.f,0.f};
  for (int base = s; base < e; base += 64){
    int idx = base + lane;
    int nb = (idx < e) ? csr[idx] : 0;
    int cnt = e - base; if (cnt > 64) cnt = 64;
    int t = 0;
    #pragma unroll 2
    for (; t + 8 <= cnt; t += 8){
      int sA = __shfl(nb, t + quad);
      int sB = __shfl(nb, t + 4 + quad);
      bf16x8 vA = ((const bf16x8*)(xb + (long)sA*128))[l16];
      bf16x8 vB = ((const bf16x8*)(xb + (long)sB*128))[l16];
      #pragma unroll
      for (int j = 0; j < 8; j++) a[j] += (float)vA[j] + (float)vB[j];
    }
    for (; t < cnt; t += 4){
      int i = t + quad;
      int ic = (i < cnt) ? i : (cnt - 1);
      int sA = __shfl(nb, ic);
      bf16x8 vA = ((const bf16x8*)(xb + (long)sA*128))[l16];
      if (i < cnt){
        #pragma unroll
        for (int j = 0; j < 8; j++) a[j] += (float)vA[j];
      }
    }
  }
  if (quad == 0){
    bf16x8 sv = ((const bf16x8*)(xb + (long)node*128))[l16];
    #pragma unroll
    for (int j = 0; j < 8; j++) a[j] += (float)sv[j];
  }
  #pragma unroll
  for (int j = 0; j < 8; j++){
    a[j] += __shfl_xor(a[j], 16);
    a[j] += __shfl_xor(a[j], 32);
  }
  if (quad == 0){
    bf16x8 r;
    #pragma unroll
    for (int j = 0; j < 8; j++) r[j] = f2bf(a[j]);
    ((bf16x8*)(hb + (long)node*128))[l16] = r;
  }
}

// y_out[M,128] = ACT2( relu(A@W1 + b1) @ W2 + b2 + res )
// Hidden in swizzled 32KB LDS; one barrier; 4 blocks/CU.
template<int ACT2>
__global__ __launch_bounds__(256, 4) void fused_mlp(const __bf16* __restrict__ A,
    const __bf16* __restrict__ wf1, const __bf16* __restrict__ wf2,
    const float* __restrict__ b1, const float* __restrict__ b2,
    const __bf16* __restrict__ res, __bf16* __restrict__ out, int M)
{
  __shared__ __bf16 H[128*128];
  int lane = threadIdx.x & 63;
  int wid = threadIdx.x >> 6;
  int quad = lane >> 4;
  long row0 = (long)blockIdx.x * 128;
  const bf16x8* w1v = (const bf16x8*)wf1;
  const bf16x8* w2v = (const bf16x8*)wf2;
  bf16x8 bv1[2][4], bv2[2][4];
  #pragma unroll
  for (int c2 = 0; c2 < 2; c2++)
    #pragma unroll
    for (int ks = 0; ks < 4; ks++){
      bv1[c2][ks] = w1v[((wid*2 + c2)*4 + ks)*64 + lane];
      bv2[c2][ks] = w2v[((wid*2 + c2)*4 + ks)*64 + lane];
    }
  int col0 = wid*32 + (lane & 15);
  float bb1_0 = b1[col0], bb1_1 = b1[col0 + 16];
  float bb2_0 = b2[col0], bb2_1 = b2[col0 + 16];
  int koff = quad << 3;
  // phase 1: H = relu(A@W1 + b1)
  #pragma unroll 2
  for (int rt = 0; rt < 8; rt++){
    long row = row0 + rt*16 + (lane & 15);
    long rowc = (row < M) ? row : (long)(M-1);
    const __bf16* ap = A + rowc*128 + koff;
    bf16x8 av[4];
    #pragma unroll
    for (int ks = 0; ks < 4; ks++)
      av[ks] = *(const bf16x8*)(ap + ks*32);
    f32x4 acc0 = {0.f,0.f,0.f,0.f}, acc1 = {0.f,0.f,0.f,0.f};
    #pragma unroll
    for (int ks = 0; ks < 4; ks++){
      acc0 = __builtin_amdgcn_mfma_f32_16x16x32_bf16(av[ks], bv1[0][ks], acc0, 0, 0, 0);
      acc1 = __builtin_amdgcn_mfma_f32_16x16x32_bf16(av[ks], bv1[1][ks], acc1, 0, 0, 0);
    }
    int r0 = rt*16 + (quad << 2);
    #pragma unroll
    for (int c2 = 0; c2 < 2; c2++){
      f32x4 acc = c2 ? acc1 : acc0;
      int col = col0 + c2*16;
      float bb = c2 ? bb1_1 : bb1_0;
      #pragma unroll
      for (int i = 0; i < 4; i++)
        H[hswz(r0 + i, col)] = f2bf(fmaxf(acc[i] + bb, 0.f));
    }
  }
  __syncthreads();
  // phase 2: out = ACT2(H@W2 + b2 + res)
  #pragma unroll 2
  for (int rt = 0; rt < 8; rt++){
    int r = rt*16 + (lane & 15);
    bf16x8 av[4];
    #pragma unroll
    for (int ks = 0; ks < 4; ks++)
      av[ks] = *(const bf16x8*)hvec(H, r, 4*ks + quad);
    f32x4 acc0 = {0.f,0.f,0.f,0.f}, acc1 = {0.f,0.f,0.f,0.f};
    #pragma unroll
    for (int ks = 0; ks < 4; ks++){
      acc0 = __builtin_amdgcn_mfma_f32_16x16x32_bf16(av[ks], bv2[0][ks], acc0, 0, 0, 0);
      acc1 = __builtin_amdgcn_mfma_f32_16x16x32_bf16(av[ks], bv2[1][ks], acc1, 0, 0, 0);
    }
    long orow0 = row0 + rt*16 + (quad << 2);
    #pragma unroll
    for (int c2 = 0; c2 < 2; c2++){
      f32x4 acc = c2 ? acc1 : acc0;
      int col = col0 + c2*16;
      float bb = c2 ? bb2_1 : bb2_0;
      #pragma unroll
      for (int i = 0; i < 4; i++){
        long orow = orow0 + i;
        if (orow < M){
          long idx = orow*128 + col;
          float v = acc[i] + bb + (float)res[idx];
          if (ACT2 == 2) v = (v > 0.f) ? v : (__expf(v) - 1.f);
          out[idx] = f2bf(v);
        }
      }
    }
  }
}

// Layer-3 MLP + JK projection, single 32KB LDS tile (H reused in place for Y3).
// Phase 3: src-major K loop (8 weight frags live at a time), 2 row-half passes.
__global__ __launch_bounds__(256, 4) void fused_mlp_jk(const __bf16* __restrict__ A,
    const __bf16* __restrict__ y1g, const __bf16* __restrict__ y2g,
    const __bf16* __restrict__ wf1, const __bf16* __restrict__ wf2,
    const __bf16* __restrict__ wfjk,
    const float* __restrict__ b1, const float* __restrict__ b2,
    const float* __restrict__ jkb, float* __restrict__ out, int M)
{
  __shared__ __bf16 H[128*128];
  int lane = threadIdx.x & 63;
  int wid = threadIdx.x >> 6;
  int quad = lane >> 4;
  long row0 = (long)blockIdx.x * 128;
  const bf16x8* w1v = (const bf16x8*)wf1;
  const bf16x8* w2v = (const bf16x8*)wf2;
  bf16x8 bv1[2][4], bv2[2][4];
  #pragma unroll
  for (int c2 = 0; c2 < 2; c2++)
    #pragma unroll
    for (int ks = 0; ks < 4; ks++){
      bv1[c2][ks] = w1v[((wid*2 + c2)*4 + ks)*64 + lane];
      bv2[c2][ks] = w2v[((wid*2 + c2)*4 + ks)*64 + lane];
    }
  int col0 = wid*32 + (lane & 15);
  float bb1_0 = b1[col0], bb1_1 = b1[col0 + 16];
  float bb2_0 = b2[col0], bb2_1 = b2[col0 + 16];
  int koff = quad << 3;
  // phase 1: H = relu(A@W1 + b1)
  #pragma unroll 2
  for (int rt = 0; rt < 8; rt++){
    long row = row0 + rt*16 + (lane & 15);
    long rowc = (row < M) ? row : (long)(M-1);
    const __bf16* ap = A + rowc*128 + koff;
    bf16x8 av[4];
    #pragma unroll
    for (int ks = 0; ks < 4; ks++)
      av[ks] = *(const bf16x8*)(ap + ks*32);
    f32x4 acc0 = {0.f,0.f,0.f,0.f}, acc1 = {0.f,0.f,0.f,0.f};
    #pragma unroll
    for (int ks = 0; ks < 4; ks++){
      acc0 = __builtin_amdgcn_mfma_f32_16x16x32_bf16(av[ks], bv1[0][ks], acc0, 0, 0, 0);
      acc1 = __builtin_amdgcn_mfma_f32_16x16x32_bf16(av[ks], bv1[1][ks], acc1, 0, 0, 0);
    }
    int r0 = rt*16 + (quad << 2);
    #pragma unroll
    for (int c2 = 0; c2 < 2; c2++){
      f32x4 acc = c2 ? acc1 : acc0;
      int col = col0 + c2*16;
      float bb = c2 ? bb1_1 : bb1_0;
      #pragma unroll
      for (int i = 0; i < 4; i++)
        H[hswz(r0 + i, col)] = f2bf(fmaxf(acc[i] + bb, 0.f));
    }
  }
  __syncthreads();
  // phase 2: H <- Y3 = H@W2 + b2 + y2  (in place; read tile -> barrier -> write tile)
  #pragma unroll 1
  for (int rt = 0; rt < 8; rt++){
    int r = rt*16 + (lane & 15);
    bf16x8 av[4];
    #pragma unroll
    for (int ks = 0; ks < 4; ks++)
      av[ks] = *(const bf16x8*)hvec(H, r, 4*ks + quad);
    f32x4 acc0 = {0.f,0.f,0.f,0.f}, acc1 = {0.f,0.f,0.f,0.f};
    #pragma unroll
    for (int ks = 0; ks < 4; ks++){
      acc0 = __builtin_amdgcn_mfma_f32_16x16x32_bf16(av[ks], bv2[0][ks], acc0, 0, 0, 0);
      acc1 = __builtin_amdgcn_mfma_f32_16x16x32_bf16(av[ks], bv2[1][ks], acc1, 0, 0, 0);
    }
    long orow0 = row0 + rt*16 + (quad << 2);
    int r0 = rt*16 + (quad << 2);
    float rv[2][4];
    #pragma unroll
    for (int c2 = 0; c2 < 2; c2++)
      #pragma unroll
      for (int i = 0; i < 4; i++){
        long orow = orow0 + i;
        rv[c2][i] = (orow < M) ? (float)y2g[orow*128 + col0 + c2*16] : 0.f;
      }
    __syncthreads();    // all reads of tile rt done before overwrite
    #pragma unroll
    for (int c2 = 0; c2 < 2; c2++){
      f32x4 acc = c2 ? acc1 : acc0;
      int col = col0 + c2*16;
      float bb = c2 ? bb2_1 : bb2_0;
      #pragma unroll
      for (int i = 0; i < 4; i++)
        H[hswz(r0 + i, col)] = f2bf(acc[i] + bb + rv[c2][i]);
    }
  }
  __syncthreads();
  // phase 3: out = [y1|y2|Y3(=H)] @ jkW + jkb  (fp32), src-major, 2 halves
  const bf16x8* wjv = (const bf16x8*)wfjk;
  float jb0 = jkb[col0], jb1 = jkb[col0 + 16];
  #pragma unroll 1
  for (int half = 0; half < 2; half++){
    f32x4 acc[4][2];
    #pragma unroll
    for (int q = 0; q < 4; q++){
      acc[q][0] = (f32x4){jb0, jb0, jb0, jb0};
      acc[q][1] = (f32x4){jb1, jb1, jb1, jb1};
    }
    #pragma unroll 1
    for (int src = 0; src < 2; src++){   // y1, y2 from global
      const __bf16* yg = src ? y2g : y1g;
      bf16x8 bv[2][4];
      #pragma unroll
      for (int c2 = 0; c2 < 2; c2++)
        #pragma unroll
        for (int ks = 0; ks < 4; ks++)
          bv[c2][ks] = wjv[(size_t)src*2048 + (size_t)((wid*2 + c2)*4 + ks)*64 + lane];
      #pragma unroll
      for (int q = 0; q < 4; q++){
        int rt = half*4 + q;
        long row = row0 + rt*16 + (lane & 15);
        long rowc = (row < M) ? row : (long)(M-1);
        const __bf16* ap = yg + rowc*128 + koff;
        bf16x8 av[4];
        #pragma unroll
        for (int ks = 0; ks < 4; ks++)
          av[ks] = *(const bf16x8*)(ap + ks*32);
        #pragma unroll
        for (int ks = 0; ks < 4; ks++){
          acc[q][0] = __builtin_amdgcn_mfma_f32_16x16x32_bf16(av[ks], bv[0][ks], acc[q][0], 0, 0, 0);
          acc[q][1] = __builtin_amdgcn_mfma_f32_16x16x32_bf16(av[ks], bv[1][ks], acc[q][1], 0, 0, 0);
        }
      }
    }
    {   // src 2: Y3 from LDS
      bf16x8 bv[2][4];
      #pragma unroll
      for (int c2 = 0; c2 < 2; c2++)
        #pragma unroll
        for (int ks = 0; ks < 4; ks++)
          bv[c2][ks] = wjv[(size_t)2*2048 + (size_t)((wid*2 + c2)*4 + ks)*64 + lane];
      #pragma unroll
      for (int q = 0; q < 4; q++){
        int rt = half*4 + q;
        int r = rt*16 + (lane & 15);
        bf16x8 av[4];
        #pragma unroll
        for (int ks = 0; ks < 4; ks++)
          av[ks] = *(const bf16x8*)hvec(H, r, 4*ks + quad);
        #pragma unroll
        for (int ks = 0; ks < 4; ks++){
          acc[q][0] = __builtin_amdgcn_mfma_f32_16x16x32_bf16(av[ks], bv[0][ks], acc[q][0], 0, 0, 0);
          acc[q][1] = __builtin_amdgcn_mfma_f32_16x16x32_bf16(av[ks], bv[1][ks], acc[q][1], 0, 0, 0);
        }
      }
    }
    #pragma unroll
    for (int q = 0; q < 4; q++){
      int rt = half*4 + q;
      long orow0 = row0 + rt*16 + (quad << 2);
      #pragma unroll
      for (int c2 = 0; c2 < 2; c2++){
        int col = col0 + c2*16;
        #pragma unroll
        for (int i = 0; i < 4; i++){
          long orow = orow0 + i;
          if (orow < M)
            out[orow*128 + col] = acc[q][c2][i];
        }
      }
    }
  }
}

extern "C" void kernel_launch(void* const* d_in, const int* in_sizes, int n_in,
                              void* d_out, int out_size, void* d_ws, size_t ws_size,
                              hipStream_t stream)
{
  const float* x   = (const float*)d_in[0];
  const int*   ei  = (const int*)d_in[1];
  const float* w1[3] = {(const float*)d_in[2], (const float*)d_in[6], (const float*)d_in[10]};
  const float* b1[3] = {(const float*)d_in[3], (const float*)d_in[7], (const float*)d_in[11]};
  const float* w2[3] = {(const float*)d_in[4], (const float*)d_in[8], (const float*)d_in[12]};
  const float* b2[3] = {(const float*)d_in[5], (const float*)d_in[9], (const float*)d_in[13]};
  const float* jkw = (const float*)d_in[14];
  const float* jkb = (const float*)d_in[15];
  int N = in_sizes[0] / 128;
  int E = in_sizes[1] / 2;
  float* outp = (float*)d_out;

  char* wptr = (char*)d_ws;
  auto alloc = [&](size_t bytes)->void*{
    void* p = (void*)wptr; wptr += (bytes + 255) & ~(size_t)255; return p;
  };
  int NBLK = (E + CHUNK - 1) / CHUNK;          // 391
  int L = NBUCK * NBLK;                        // 200K
  int* rs    = (int*)alloc((size_t)(N+1)*4);
  int* csr   = (int*)alloc((size_t)E*4);
  int* tpack = (int*)alloc((size_t)E*4);
  int* cnt   = (int*)alloc((size_t)L*4);
  int* off   = (int*)alloc((size_t)L*4);
  __bf16* y[3];
  for (int i = 0; i < 3; i++) y[i] = (__bf16*)alloc((size_t)N*128*2);
  __bf16* hb = (__bf16*)alloc((size_t)N*128*2);
  __bf16* wf = (__bf16*)alloc((size_t)9*16384*2);
  int nsb = (L + 2047) / 2048;                 // scan blocks (98)
  int* bsum = (int*)alloc((size_t)nsb*4);
  int* boff = (int*)alloc((size_t)nsb*4);

  WPack pk;
  pk.p[0] = w1[0]; pk.p[1] = w2[0];
  pk.p[2] = w1[1]; pk.p[3] = w2[1];
  pk.p[4] = w1[2]; pk.p[5] = w2[2];
  pk.p[6] = jkw; pk.p[7] = jkw + 16384; pk.p[8] = jkw + 32768;
  int n8 = N*128/8;
  prep_kernel<<<576 + (n8 + 255)/256, 256, 0, stream>>>(pk, wf, x, y[0], n8);

  p1_count<<<NBLK, 256, 0, stream>>>(ei, E, NBLK, cnt);
  scan1_kernel<<<nsb, 256, 0, stream>>>(cnt, bsum, L);
  scan2_kernel<<<1, 256, 0, stream>>>(bsum, boff, nsb, rs + N);   // rs[N] = E
  scan3_kernel<<<nsb, 256, 0, stream>>>(cnt, boff, off, L);
  p3_scatter<<<NBLK, 256, 0, stream>>>(ei, E, NBLK, off, tpack);
  p4_build<<<NBUCK, 256, 0, stream>>>(tpack, off, NBLK, E, N, rs, csr);

  int gemm_blocks = (N + 127)/128;
  for (int l = 0; l < 3; l++){
    agg_kernel<<<(N + 3)/4, 256, 0, stream>>>(y[l], rs, csr, hb, N);
    if (l < 2)
      fused_mlp<2><<<gemm_blocks, 256, 0, stream>>>(hb, wf + (size_t)(2*l)*16384, wf + (size_t)(2*l+1)*16384,
                                                    b1[l], b2[l], y[l], y[l+1], N);
    else
      fused_mlp_jk<<<gemm_blocks, 256, 0, stream>>>(hb, y[1], y[2],
                                                    wf + (size_t)4*16384, wf + (size_t)5*16384, wf + (size_t)6*16384,
                                                    b1[2], b2[2], jkb, outp, N);
  }
}

// Round 10
// 383.454 us; speedup vs baseline: 2.8660x; 1.0221x over previous
//
#include <hip/hip_runtime.h>

typedef __bf16 bf16x8 __attribute__((ext_vector_type(8)));
typedef float f32x4 __attribute__((ext_vector_type(4)));

#define CHUNK 4096
#define NBUCK 512

struct WPack { const float* p[9]; };

__device__ inline __bf16 f2bf(float f){ return (__bf16)f; }

// Swizzled 64x128 bf16 LDS tile (16KB, no pad). Element (r,c) lives at
// r*128 + (((c>>3) ^ (r&7))<<3) + (c&7).
__device__ inline int hswz(int r, int c){
  return (r << 7) + ((((c >> 3) ^ (r & 7)) << 3) | (c & 7));
}
__device__ inline const __bf16* hvec(const __bf16* H, int r, int g){  // g = 8-elem granule 0..15
  return H + (r << 7) + (((g ^ (r & 7)) & 15) << 3);
}

// Combined prep: blocks [0,576) convert 9 fp32 128x128 weight mats into MFMA
// B-fragment layout (bf16); blocks [576,...) bulk-convert x fp32->bf16.
// wf element index: m*16384 + c*2048 + ks*512 + lane*8 + j
//   holds W[k][col], k = ks*32 + (lane>>4)*8 + j, col = c*16 + (lane&15)
__global__ __launch_bounds__(256) void prep_kernel(WPack pk, __bf16* __restrict__ wf,
    const float* __restrict__ x, __bf16* __restrict__ xb, int n8){
  int b = blockIdx.x, t = threadIdx.x;
  if (b < 576){
    int tid = b*256 + t;
    int m = tid >> 14;
    int r = tid & 16383;
    int j = r & 7;
    int lane = (r >> 3) & 63;
    int ks = (r >> 9) & 3;
    int c = r >> 11;
    int k = ks*32 + ((lane>>4)<<3) + j;
    int col = (c<<4) + (lane & 15);
    wf[tid] = f2bf(pk.p[m][k*128 + col]);
  } else {
    int i = (b - 576)*256 + t;
    if (i >= n8) return;
    f32x4 a = ((const f32x4*)x)[2*i];
    f32x4 bb = ((const f32x4*)x)[2*i+1];
    bf16x8 r;
    r[0]=f2bf(a[0]); r[1]=f2bf(a[1]); r[2]=f2bf(a[2]); r[3]=f2bf(a[3]);
    r[4]=f2bf(bb[0]); r[5]=f2bf(bb[1]); r[6]=f2bf(bb[2]); r[7]=f2bf(bb[3]);
    ((bf16x8*)xb)[i] = r;
  }
}

// ---- CSR build via two-level bucket sort (no global atomics) ----
__global__ __launch_bounds__(256) void p1_count(const int* __restrict__ ei, int E, int NBLK,
    int* __restrict__ cnt){
  __shared__ int h[NBUCK];
  int b = blockIdx.x, t = threadIdx.x;
  h[t] = 0; h[t + 256] = 0;
  __syncthreads();
  int base = b*CHUNK;
  int lim = E - base; if (lim > CHUNK) lim = CHUNK;
  for (int i = t; i < lim; i += 256)
    atomicAdd(&h[ei[E + base + i] >> 8], 1);     // dst row
  __syncthreads();
  cnt[t*NBLK + b] = h[t];
  cnt[(t + 256)*NBLK + b] = h[t + 256];
}

__global__ __launch_bounds__(256) void scan1_kernel(const int* __restrict__ cnt, int* __restrict__ bsum, int L){
  __shared__ int sh[256];
  int b = blockIdx.x, t = threadIdx.x;
  int base = b*2048 + t*8;
  int s = 0;
  #pragma unroll
  for (int j = 0; j < 8; j++){ int i = base + j; if (i < L) s += cnt[i]; }
  sh[t] = s; __syncthreads();
  for (int off = 128; off > 0; off >>= 1){
    if (t < off) sh[t] += sh[t + off];
    __syncthreads();
  }
  if (t == 0) bsum[b] = sh[0];
}

__global__ __launch_bounds__(256) void scan2_kernel(const int* __restrict__ bsum, int* __restrict__ boff,
                                                    int NB, int* __restrict__ total_out){
  __shared__ int sh[256];
  int t = threadIdx.x;
  int v = (t < NB) ? bsum[t] : 0;
  sh[t] = v; __syncthreads();
  for (int off = 1; off < 256; off <<= 1){
    int u = (t >= off) ? sh[t - off] : 0;
    __syncthreads();
    sh[t] += u;
    __syncthreads();
  }
  if (t < NB) boff[t] = sh[t] - v;          // exclusive
  if (t == 255) *total_out = sh[255];       // rs[N] = E
}

__global__ __launch_bounds__(256) void scan3_kernel(const int* __restrict__ cnt, const int* __restrict__ boff,
                                                    int* __restrict__ off, int L){
  __shared__ int sh[256];
  int b = blockIdx.x, t = threadIdx.x;
  int base = b*2048 + t*8;
  int loc[8]; int s = 0;
  #pragma unroll
  for (int j = 0; j < 8; j++){ int i = base + j; int d = (i < L) ? cnt[i] : 0; loc[j] = d; s += d; }
  sh[t] = s; __syncthreads();
  for (int o = 1; o < 256; o <<= 1){
    int u = (t >= o) ? sh[t - o] : 0;
    __syncthreads();
    sh[t] += u;
    __syncthreads();
  }
  int excl = boff[b] + sh[t] - s;
  #pragma unroll
  for (int j = 0; j < 8; j++){ int i = base + j; if (i < L) off[i] = excl; excl += loc[j]; }
}

__global__ __launch_bounds__(256) void p3_scatter(const int* __restrict__ ei, int E, int NBLK,
    const int* __restrict__ off, int* __restrict__ tpack){
  __shared__ int cur[NBUCK];
  int b = blockIdx.x, t = threadIdx.x;
  cur[t]       = off[t*NBLK + b];
  cur[t + 256] = off[(t + 256)*NBLK + b];
  __syncthreads();
  int base = b*CHUNK;
  int lim = E - base; if (lim > CHUNK) lim = CHUNK;
  for (int i = t; i < lim; i += 256){
    int s = ei[base + i];
    int d = ei[E + base + i];
    int p = atomicAdd(&cur[d >> 8], 1);   // LDS atomic: global slot
    tpack[p] = (s << 8) | (d & 255);
  }
}

__global__ __launch_bounds__(256) void p4_build(const int* __restrict__ tpack,
    const int* __restrict__ off, int NBLK, int E, int N,
    int* __restrict__ rs, int* __restrict__ csr){
  __shared__ int dc[256], sc[256];
  int q = blockIdx.x, t = threadIdx.x;
  int bstart = off[q*NBLK];
  int bend = (q == NBUCK-1) ? E : off[(q+1)*NBLK];
  dc[t] = 0;
  __syncthreads();
  for (int i = bstart + t; i < bend; i += 256)
    atomicAdd(&dc[tpack[i] & 255], 1);
  __syncthreads();
  int v = dc[t];
  sc[t] = v; __syncthreads();
  for (int o = 1; o < 256; o <<= 1){
    int u = (t >= o) ? sc[t - o] : 0;
    __syncthreads();
    sc[t] += u;
    __syncthreads();
  }
  int ex = sc[t] - v;                  // exclusive within bucket
  int gd = q*256 + t;
  if (gd < N) rs[gd] = bstart + ex;
  __syncthreads();
  dc[t] = ex;                          // reuse as cursor
  __syncthreads();
  for (int i = bstart + t; i < bend; i += 256){
    int p = tpack[i];
    int r = atomicAdd(&dc[p & 255], 1);
    csr[bstart + r] = p >> 8;
  }
}

// h[i] = x[i] + sum_{j in N(i)} x[j]   (unchanged; at fabric byte floor)
__global__ __launch_bounds__(256) void agg_kernel(const __bf16* __restrict__ xb,
    const int* __restrict__ rs, const int* __restrict__ csr,
    __bf16* __restrict__ hb, int N)
{
  int node = blockIdx.x*4 + (threadIdx.x >> 6);
  if (node >= N) return;
  int lane = threadIdx.x & 63;
  int quad = lane >> 4;
  int l16  = lane & 15;
  int s = rs[node], e = rs[node+1];
  float a[8] = {0.f,0.f,0.f,0.f,0.f,0.f,0.f,0.f};
  for (int base = s; base < e; base += 64){
    int idx = base + lane;
    int nb = (idx < e) ? csr[idx] : 0;
    int cnt = e - base; if (cnt > 64) cnt = 64;
    int t = 0;
    #pragma unroll 2
    for (; t + 8 <= cnt; t += 8){
      int sA = __shfl(nb, t + quad);
      int sB = __shfl(nb, t + 4 + quad);
      bf16x8 vA = ((const bf16x8*)(xb + (long)sA*128))[l16];
      bf16x8 vB = ((const bf16x8*)(xb + (long)sB*128))[l16];
      #pragma unroll
      for (int j = 0; j < 8; j++) a[j] += (float)vA[j] + (float)vB[j];
    }
    for (; t < cnt; t += 4){
      int i = t + quad;
      int ic = (i < cnt) ? i : (cnt - 1);
      int sA = __shfl(nb, ic);
      bf16x8 vA = ((const bf16x8*)(xb + (long)sA*128))[l16];
      if (i < cnt){
        #pragma unroll
        for (int j = 0; j < 8; j++) a[j] += (float)vA[j];
      }
    }
  }
  if (quad == 0){
    bf16x8 sv = ((const bf16x8*)(xb + (long)node*128))[l16];
    #pragma unroll
    for (int j = 0; j < 8; j++) a[j] += (float)sv[j];
  }
  #pragma unroll
  for (int j = 0; j < 8; j++){
    a[j] += __shfl_xor(a[j], 16);
    a[j] += __shfl_xor(a[j], 32);
  }
  if (quad == 0){
    bf16x8 r;
    #pragma unroll
    for (int j = 0; j < 8; j++) r[j] = f2bf(a[j]);
    ((bf16x8*)(hb + (long)node*128))[l16] = r;
  }
}

// y_out[64-row tile] = ACT2( relu(A@W1 + b1) @ W2 + b2 + res )
// 64-row blocks: 16KB swizzled LDS hidden, grid 2x, ~6 blocks/CU.
template<int ACT2>
__global__ __launch_bounds__(256, 4) void fused_mlp(const __bf16* __restrict__ A,
    const __bf16* __restrict__ wf1, const __bf16* __restrict__ wf2,
    const float* __restrict__ b1, const float* __restrict__ b2,
    const __bf16* __restrict__ res, __bf16* __restrict__ out, int M)
{
  __shared__ __bf16 H[64*128];
  int lane = threadIdx.x & 63;
  int wid = threadIdx.x >> 6;
  int quad = lane >> 4;
  long row0 = (long)blockIdx.x * 64;
  const bf16x8* w1v = (const bf16x8*)wf1;
  const bf16x8* w2v = (const bf16x8*)wf2;
  bf16x8 bv1[2][4], bv2[2][4];
  #pragma unroll
  for (int c2 = 0; c2 < 2; c2++)
    #pragma unroll
    for (int ks = 0; ks < 4; ks++){
      bv1[c2][ks] = w1v[((wid*2 + c2)*4 + ks)*64 + lane];
      bv2[c2][ks] = w2v[((wid*2 + c2)*4 + ks)*64 + lane];
    }
  int col0 = wid*32 + (lane & 15);
  float bb1_0 = b1[col0], bb1_1 = b1[col0 + 16];
  float bb2_0 = b2[col0], bb2_1 = b2[col0 + 16];
  int koff = quad << 3;
  // phase 1: H = relu(A@W1 + b1)
  #pragma unroll 2
  for (int rt = 0; rt < 4; rt++){
    long row = row0 + rt*16 + (lane & 15);
    long rowc = (row < M) ? row : (long)(M-1);
    const __bf16* ap = A + rowc*128 + koff;
    bf16x8 av[4];
    #pragma unroll
    for (int ks = 0; ks < 4; ks++)
      av[ks] = *(const bf16x8*)(ap + ks*32);
    f32x4 acc0 = {0.f,0.f,0.f,0.f}, acc1 = {0.f,0.f,0.f,0.f};
    #pragma unroll
    for (int ks = 0; ks < 4; ks++){
      acc0 = __builtin_amdgcn_mfma_f32_16x16x32_bf16(av[ks], bv1[0][ks], acc0, 0, 0, 0);
      acc1 = __builtin_amdgcn_mfma_f32_16x16x32_bf16(av[ks], bv1[1][ks], acc1, 0, 0, 0);
    }
    int r0 = rt*16 + (quad << 2);
    #pragma unroll
    for (int c2 = 0; c2 < 2; c2++){
      f32x4 acc = c2 ? acc1 : acc0;
      int col = col0 + c2*16;
      float bb = c2 ? bb1_1 : bb1_0;
      #pragma unroll
      for (int i = 0; i < 4; i++)
        H[hswz(r0 + i, col)] = f2bf(fmaxf(acc[i] + bb, 0.f));
    }
  }
  __syncthreads();
  // phase 2: out = ACT2(H@W2 + b2 + res)
  #pragma unroll 2
  for (int rt = 0; rt < 4; rt++){
    int r = rt*16 + (lane & 15);
    bf16x8 av[4];
    #pragma unroll
    for (int ks = 0; ks < 4; ks++)
      av[ks] = *(const bf16x8*)hvec(H, r, 4*ks + quad);
    f32x4 acc0 = {0.f,0.f,0.f,0.f}, acc1 = {0.f,0.f,0.f,0.f};
    #pragma unroll
    for (int ks = 0; ks < 4; ks++){
      acc0 = __builtin_amdgcn_mfma_f32_16x16x32_bf16(av[ks], bv2[0][ks], acc0, 0, 0, 0);
      acc1 = __builtin_amdgcn_mfma_f32_16x16x32_bf16(av[ks], bv2[1][ks], acc1, 0, 0, 0);
    }
    long orow0 = row0 + rt*16 + (quad << 2);
    #pragma unroll
    for (int c2 = 0; c2 < 2; c2++){
      f32x4 acc = c2 ? acc1 : acc0;
      int col = col0 + c2*16;
      float bb = c2 ? bb2_1 : bb2_0;
      #pragma unroll
      for (int i = 0; i < 4; i++){
        long orow = orow0 + i;
        if (orow < M){
          long idx = orow*128 + col;
          float v = acc[i] + bb + (float)res[idx];
          if (ACT2 == 2) v = (v > 0.f) ? v : (__expf(v) - 1.f);
          out[idx] = f2bf(v);
        }
      }
    }
  }
}

// Layer-3 MLP + JK projection, 64-row blocks, 16KB LDS (H reused for Y3).
// Phase 3: src-major K loop, single pass (acc[4][2], 8 weight frags live).
__global__ __launch_bounds__(256, 4) void fused_mlp_jk(const __bf16* __restrict__ A,
    const __bf16* __restrict__ y1g, const __bf16* __restrict__ y2g,
    const __bf16* __restrict__ wf1, const __bf16* __restrict__ wf2,
    const __bf16* __restrict__ wfjk,
    const float* __restrict__ b1, const float* __restrict__ b2,
    const float* __restrict__ jkb, float* __restrict__ out, int M)
{
  __shared__ __bf16 H[64*128];
  int lane = threadIdx.x & 63;
  int wid = threadIdx.x >> 6;
  int quad = lane >> 4;
  long row0 = (long)blockIdx.x * 64;
  const bf16x8* w1v = (const bf16x8*)wf1;
  const bf16x8* w2v = (const bf16x8*)wf2;
  bf16x8 bv1[2][4], bv2[2][4];
  #pragma unroll
  for (int c2 = 0; c2 < 2; c2++)
    #pragma unroll
    for (int ks = 0; ks < 4; ks++){
      bv1[c2][ks] = w1v[((wid*2 + c2)*4 + ks)*64 + lane];
      bv2[c2][ks] = w2v[((wid*2 + c2)*4 + ks)*64 + lane];
    }
  int col0 = wid*32 + (lane & 15);
  float bb1_0 = b1[col0], bb1_1 = b1[col0 + 16];
  float bb2_0 = b2[col0], bb2_1 = b2[col0 + 16];
  int koff = quad << 3;
  // phase 1: H = relu(A@W1 + b1)
  #pragma unroll 2
  for (int rt = 0; rt < 4; rt++){
    long row = row0 + rt*16 + (lane & 15);
    long rowc = (row < M) ? row : (long)(M-1);
    const __bf16* ap = A + rowc*128 + koff;
    bf16x8 av[4];
    #pragma unroll
    for (int ks = 0; ks < 4; ks++)
      av[ks] = *(const bf16x8*)(ap + ks*32);
    f32x4 acc0 = {0.f,0.f,0.f,0.f}, acc1 = {0.f,0.f,0.f,0.f};
    #pragma unroll
    for (int ks = 0; ks < 4; ks++){
      acc0 = __builtin_amdgcn_mfma_f32_16x16x32_bf16(av[ks], bv1[0][ks], acc0, 0, 0, 0);
      acc1 = __builtin_amdgcn_mfma_f32_16x16x32_bf16(av[ks], bv1[1][ks], acc1, 0, 0, 0);
    }
    int r0 = rt*16 + (quad << 2);
    #pragma unroll
    for (int c2 = 0; c2 < 2; c2++){
      f32x4 acc = c2 ? acc1 : acc0;
      int col = col0 + c2*16;
      float bb = c2 ? bb1_1 : bb1_0;
      #pragma unroll
      for (int i = 0; i < 4; i++)
        H[hswz(r0 + i, col)] = f2bf(fmaxf(acc[i] + bb, 0.f));
    }
  }
  __syncthreads();
  // phase 2: H <- Y3 = H@W2 + b2 + y2  (in place; read tile -> barrier -> write)
  #pragma unroll 1
  for (int rt = 0; rt < 4; rt++){
    int r = rt*16 + (lane & 15);
    bf16x8 av[4];
    #pragma unroll
    for (int ks = 0; ks < 4; ks++)
      av[ks] = *(const bf16x8*)hvec(H, r, 4*ks + quad);
    f32x4 acc0 = {0.f,0.f,0.f,0.f}, acc1 = {0.f,0.f,0.f,0.f};
    #pragma unroll
    for (int ks = 0; ks < 4; ks++){
      acc0 = __builtin_amdgcn_mfma_f32_16x16x32_bf16(av[ks], bv2[0][ks], acc0, 0, 0, 0);
      acc1 = __builtin_amdgcn_mfma_f32_16x16x32_bf16(av[ks], bv2[1][ks], acc1, 0, 0, 0);
    }
    long orow0 = row0 + rt*16 + (quad << 2);
    int r0 = rt*16 + (quad << 2);
    float rv[2][4];
    #pragma unroll
    for (int c2 = 0; c2 < 2; c2++)
      #pragma unroll
      for (int i = 0; i < 4; i++){
        long orow = orow0 + i;
        rv[c2][i] = (orow < M) ? (float)y2g[orow*128 + col0 + c2*16] : 0.f;
      }
    __syncthreads();    // all reads of tile rt done before overwrite
    #pragma unroll
    for (int c2 = 0; c2 < 2; c2++){
      f32x4 acc = c2 ? acc1 : acc0;
      int col = col0 + c2*16;
      float bb = c2 ? bb2_1 : bb2_0;
      #pragma unroll
      for (int i = 0; i < 4; i++)
        H[hswz(r0 + i, col)] = f2bf(acc[i] + bb + rv[c2][i]);
    }
  }
  __syncthreads();
  // phase 3: out = [y1|y2|Y3(=H)] @ jkW + jkb  (fp32), src-major, single pass
  const bf16x8* wjv = (const bf16x8*)wfjk;
  float jb0 = jkb[col0], jb1 = jkb[col0 + 16];
  f32x4 acc[4][2];
  #pragma unroll
  for (int q = 0; q < 4; q++){
    acc[q][0] = (f32x4){jb0, jb0, jb0, jb0};
    acc[q][1] = (f32x4){jb1, jb1, jb1, jb1};
  }
  #pragma unroll 1
  for (int src = 0; src < 2; src++){   // y1, y2 from global
    const __bf16* yg = src ? y2g : y1g;
    bf16x8 bv[2][4];
    #pragma unroll
    for (int c2 = 0; c2 < 2; c2++)
      #pragma unroll
      for (int ks = 0; ks < 4; ks++)
        bv[c2][ks] = wjv[(size_t)src*2048 + (size_t)((wid*2 + c2)*4 + ks)*64 + lane];
    #pragma unroll
    for (int q = 0; q < 4; q++){
      long row = row0 + q*16 + (lane & 15);
      long rowc = (row < M) ? row : (long)(M-1);
      const __bf16* ap = yg + rowc*128 + koff;
      bf16x8 av[4];
      #pragma unroll
      for (int ks = 0; ks < 4; ks++)
        av[ks] = *(const bf16x8*)(ap + ks*32);
      #pragma unroll
      for (int ks = 0; ks < 4; ks++){
        acc[q][0] = __builtin_amdgcn_mfma_f32_16x16x32_bf16(av[ks], bv[0][ks], acc[q][0], 0, 0, 0);
        acc[q][1] = __builtin_amdgcn_mfma_f32_16x16x32_bf16(av[ks], bv[1][ks], acc[q][1], 0, 0, 0);
      }
    }
  }
  {   // src 2: Y3 from LDS
    bf16x8 bv[2][4];
    #pragma unroll
    for (int c2 = 0; c2 < 2; c2++)
      #pragma unroll
      for (int ks = 0; ks < 4; ks++)
        bv[c2][ks] = wjv[(size_t)2*2048 + (size_t)((wid*2 + c2)*4 + ks)*64 + lane];
    #pragma unroll
    for (int q = 0; q < 4; q++){
      int r = q*16 + (lane & 15);
      bf16x8 av[4];
      #pragma unroll
      for (int ks = 0; ks < 4; ks++)
        av[ks] = *(const bf16x8*)hvec(H, r, 4*ks + quad);
      #pragma unroll
      for (int ks = 0; ks < 4; ks++){
        acc[q][0] = __builtin_amdgcn_mfma_f32_16x16x32_bf16(av[ks], bv[0][ks], acc[q][0], 0, 0, 0);
        acc[q][1] = __builtin_amdgcn_mfma_f32_16x16x32_bf16(av[ks], bv[1][ks], acc[q][1], 0, 0, 0);
      }
    }
  }
  #pragma unroll
  for (int q = 0; q < 4; q++){
    long orow0 = row0 + q*16 + (quad << 2);
    #pragma unroll
    for (int c2 = 0; c2 < 2; c2++){
      int col = col0 + c2*16;
      #pragma unroll
      for (int i = 0; i < 4; i++){
        long orow = orow0 + i;
        if (orow < M)
          out[orow*128 + col] = acc[q][c2][i];
      }
    }
  }
}

extern "C" void kernel_launch(void* const* d_in, const int* in_sizes, int n_in,
                              void* d_out, int out_size, void* d_ws, size_t ws_size,
                              hipStream_t stream)
{
  const float* x   = (const float*)d_in[0];
  const int*   ei  = (const int*)d_in[1];
  const float* w1[3] = {(const float*)d_in[2], (const float*)d_in[6], (const float*)d_in[10]};
  const float* b1[3] = {(const float*)d_in[3], (const float*)d_in[7], (const float*)d_in[11]};
  const float* w2[3] = {(const float*)d_in[4], (const float*)d_in[8], (const float*)d_in[12]};
  const float* b2[3] = {(const float*)d_in[5], (const float*)d_in[9], (const float*)d_in[13]};
  const float* jkw = (const float*)d_in[14];
  const float* jkb = (const float*)d_in[15];
  int N = in_sizes[0] / 128;
  int E = in_sizes[1] / 2;
  float* outp = (float*)d_out;

  char* wptr = (char*)d_ws;
  auto alloc = [&](size_t bytes)->void*{
    void* p = (void*)wptr; wptr += (bytes + 255) & ~(size_t)255; return p;
  };
  int NBLK = (E + CHUNK - 1) / CHUNK;          // 391
  int L = NBUCK * NBLK;                        // 200K
  int* rs    = (int*)alloc((size_t)(N+1)*4);
  int* csr   = (int*)alloc((size_t)E*4);
  int* tpack = (int*)alloc((size_t)E*4);
  int* cnt   = (int*)alloc((size_t)L*4);
  int* off   = (int*)alloc((size_t)L*4);
  __bf16* y[3];
  for (int i = 0; i < 3; i++) y[i] = (__bf16*)alloc((size_t)N*128*2);
  __bf16* hb = (__bf16*)alloc((size_t)N*128*2);
  __bf16* wf = (__bf16*)alloc((size_t)9*16384*2);
  int nsb = (L + 2047) / 2048;                 // scan blocks (98)
  int* bsum = (int*)alloc((size_t)nsb*4);
  int* boff = (int*)alloc((size_t)nsb*4);

  WPack pk;
  pk.p[0] = w1[0]; pk.p[1] = w2[0];
  pk.p[2] = w1[1]; pk.p[3] = w2[1];
  pk.p[4] = w1[2]; pk.p[5] = w2[2];
  pk.p[6] = jkw; pk.p[7] = jkw + 16384; pk.p[8] = jkw + 32768;
  int n8 = N*128/8;
  prep_kernel<<<576 + (n8 + 255)/256, 256, 0, stream>>>(pk, wf, x, y[0], n8);

  p1_count<<<NBLK, 256, 0, stream>>>(ei, E, NBLK, cnt);
  scan1_kernel<<<nsb, 256, 0, stream>>>(cnt, bsum, L);
  scan2_kernel<<<1, 256, 0, stream>>>(bsum, boff, nsb, rs + N);   // rs[N] = E
  scan3_kernel<<<nsb, 256, 0, stream>>>(cnt, boff, off, L);
  p3_scatter<<<NBLK, 256, 0, stream>>>(ei, E, NBLK, off, tpack);
  p4_build<<<NBUCK, 256, 0, stream>>>(tpack, off, NBLK, E, N, rs, csr);

  int gemm_blocks = (N + 63)/64;
  for (int l = 0; l < 3; l++){
    agg_kernel<<<(N + 3)/4, 256, 0, stream>>>(y[l], rs, csr, hb, N);
    if (l < 2)
      fused_mlp<2><<<gemm_blocks, 256, 0, stream>>>(hb, wf + (size_t)(2*l)*16384, wf + (size_t)(2*l+1)*16384,
                                                    b1[l], b2[l], y[l], y[l+1], N);
    else
      fused_mlp_jk<<<gemm_blocks, 256, 0, stream>>>(hb, y[1], y[2],
                                                    wf + (size_t)4*16384, wf + (size_t)5*16384, wf + (size_t)6*16384,
                                                    b1[2], b2[2], jkb, outp, N);
  }
}